// Round 3
// baseline (855.610 us; speedup 1.0000x reference)
//
#include <hip/hip_runtime.h>
#include <hip/hip_bf16.h>
#include <math.h>

#define CD 128
#define HH 4
#define DH 32
#define LL 2

using bf16 = __hip_bfloat16;
using bf16x8 = __attribute__((ext_vector_type(8))) short;  // 8 bf16 (4 VGPRs)
using f32x4 = __attribute__((ext_vector_type(4))) float;

__device__ __forceinline__ float bfbits2f(unsigned int s) {
  return __uint_as_float(s << 16);
}

__device__ __forceinline__ unsigned short f2bfbits(float f) {
  unsigned int u = __float_as_uint(f);
  unsigned int r = (u + 0x7fff + ((u >> 16) & 1)) >> 16;  // RNE
  return (unsigned short)r;
}

__device__ __forceinline__ float gelu_f(float x) {
  return 0.5f * x * (1.0f + erff(x * 0.70710678118654752f));
}

// ---- detect input formats: flags[0]=floats-are-f32, flags[1]=edge-index-is-i64 ----
__global__ void k_detect(const void* __restrict__ x, const int* __restrict__ ei,
                         int* __restrict__ flags) {
  __shared__ int cnt_f32, cnt_i32;
  if (threadIdx.x == 0) { cnt_f32 = 0; cnt_i32 = 0; }
  __syncthreads();
  int t = threadIdx.x;  // 128 threads
  unsigned short u = ((const unsigned short*)x)[2 * t];
  float v = bfbits2f((unsigned int)u);
  float av = fabsf(v);
  if (av != 0.f && (av > 1e8f || av < 1e-8f)) atomicAdd(&cnt_f32, 1);
  if (t < 64) {
    if (((const int*)ei)[2 * t + 1] != 0) atomicAdd(&cnt_i32, 1);
  }
  __syncthreads();
  if (threadIdx.x == 0) {
    flags[0] = (cnt_f32 > 8) ? 1 : 0;
    flags[1] = (cnt_i32 == 0) ? 1 : 0;
  }
}

// ---- x -> f32 hbuf AND bf16 hbuf16 ----
__global__ void k_cvt_x(const void* __restrict__ in, float* __restrict__ out,
                        unsigned short* __restrict__ out16, int n,
                        const int* __restrict__ flags) {
  int i = blockIdx.x * blockDim.x + threadIdx.x;
  if (i >= n) return;
  float v = flags[0] ? ((const float*)in)[i]
                     : bfbits2f((unsigned int)((const unsigned short*)in)[i]);
  out[i] = v;
  out16[i] = f2bfbits(v);
}

// ---- all parameter tensors -> contiguous f32 block, one launch ----
#define NSEG 14
struct SegTab {
  const void* src[NSEG];
  int off[NSEG];
  int total;
};
__global__ void k_cvt_params(SegTab tab, float* __restrict__ dst,
                             const int* __restrict__ flags) {
  int i = blockIdx.x * 256 + threadIdx.x;
  if (i >= tab.total) return;
  int seg = 0;
#pragma unroll
  for (int k = 1; k < NSEG; k++)
    if (i >= tab.off[k]) seg = k;
  int j = i - tab.off[seg];
  const void* src = tab.src[seg];
  dst[i] = flags[0] ? ((const float*)src)[j]
                    : bfbits2f((unsigned int)((const unsigned short*)src)[j]);
}

__device__ __forceinline__ int edge_idx(const int* __restrict__ ei, long pos, int is64) {
  return is64 ? ei[2 * pos] : ei[pos];
}

// ---- fold relation transforms into K/V weights: emit bf16 TRANSPOSED WT[n][k] ----
__global__ void k_eff(const float* __restrict__ Wk, const float* __restrict__ bk,
                      const float* __restrict__ Wv, const float* __restrict__ bv,
                      const float* __restrict__ ar, const float* __restrict__ mr,
                      unsigned short* __restrict__ wkeT, float* __restrict__ bke,
                      unsigned short* __restrict__ wveT, float* __restrict__ bve) {
  int c = blockIdx.x, h = blockIdx.y, z = blockIdx.z;
  int l = z >> 1, which = z & 1;
  int e = threadIdx.x;
  const float* W = (which ? Wv : Wk) + (size_t)l * CD * CD;
  const float* B = (which ? bv : bk) + (size_t)l * CD;
  const float* R = (which ? mr : ar) + (size_t)l * HH * DH * DH + h * DH * DH;
  unsigned short* WoT = (which ? wveT : wkeT) + (size_t)l * CD * CD;
  float* Bo = (which ? bve : bke) + (size_t)l * CD;
  float acc = 0.f;
  if (c < CD) {
#pragma unroll
    for (int d = 0; d < DH; d++) acc += W[c * CD + h * DH + d] * R[d * DH + e];
    WoT[(size_t)(h * DH + e) * CD + c] = f2bfbits(acc);  // transposed [n][k]
  } else {
#pragma unroll
    for (int d = 0; d < DH; d++) acc += B[h * DH + d] * R[d * DH + e];
    Bo[h * DH + e] = acc;
  }
}

// ---- transpose Wq/Wa to bf16 WT[n][k], both layers ----
__global__ void k_wt(const float* __restrict__ Wq, const float* __restrict__ Wa,
                     unsigned short* __restrict__ WqT, unsigned short* __restrict__ WaT) {
  int cout = blockIdx.x, z = blockIdx.y;
  int l = z >> 1, which = z & 1;
  int cin = threadIdx.x;
  const float* W = (which ? Wa : Wq) + (size_t)l * CD * CD;
  unsigned short* WT = (which ? WaT : WqT) + (size_t)l * CD * CD;
  WT[(size_t)cout * CD + cin] = f2bfbits(W[(size_t)cin * CD + cout]);
}

// ==== fused single-pass q/k/v MFMA GEMM: A read ONCE per block (was 3x via
// grid.y). q -> f32; k -> kv[row][0:128]; v -> kv[row][128:256] (bf16).
// 3x32 acc VGPRs + frags ~ 140 VGPR, no LDS. ====
__global__ __launch_bounds__(256) void k_gemm_qkv3(
    const unsigned short* __restrict__ A,
    const unsigned short* __restrict__ wq, const unsigned short* __restrict__ wk,
    const unsigned short* __restrict__ wv,
    const float* __restrict__ bq, const float* __restrict__ bk,
    const float* __restrict__ bv,
    float* __restrict__ qout, unsigned short* __restrict__ kvout, int nrows) {
  const int w = threadIdx.x >> 6;
  const int l = threadIdx.x & 63;
  const int r0 = blockIdx.x * 64 + w * 16;
  if (r0 >= nrows) return;
  const int lrow = l & 15;
  const int quad = l >> 4;
  const int k0 = quad * 8;

  f32x4 accq[8], acck[8], accv[8];
#pragma unroll
  for (int ct = 0; ct < 8; ct++) {
    float b0 = bq[ct * 16 + lrow];
    float b1 = bk[ct * 16 + lrow];
    float b2 = bv[ct * 16 + lrow];
    accq[ct] = (f32x4){b0, b0, b0, b0};
    acck[ct] = (f32x4){b1, b1, b1, b1};
    accv[ct] = (f32x4){b2, b2, b2, b2};
  }
  int ar = r0 + lrow;
  if (ar >= nrows) ar = nrows - 1;
  const unsigned short* Ap = A + (size_t)ar * CD;
#pragma unroll
  for (int kc = 0; kc < 4; kc++) {
    bf16x8 af = *(const bf16x8*)(Ap + kc * 32 + k0);
#pragma unroll
    for (int ct = 0; ct < 8; ct++) {
      const size_t wo = (size_t)(ct * 16 + lrow) * CD + kc * 32 + k0;
      accq[ct] = __builtin_amdgcn_mfma_f32_16x16x32_bf16(
          af, *(const bf16x8*)(wq + wo), accq[ct], 0, 0, 0);
      acck[ct] = __builtin_amdgcn_mfma_f32_16x16x32_bf16(
          af, *(const bf16x8*)(wk + wo), acck[ct], 0, 0, 0);
      accv[ct] = __builtin_amdgcn_mfma_f32_16x16x32_bf16(
          af, *(const bf16x8*)(wv + wo), accv[ct], 0, 0, 0);
    }
  }
#pragma unroll
  for (int ct = 0; ct < 8; ct++) {
#pragma unroll
    for (int i = 0; i < 4; i++) {
      int gr = r0 + quad * 4 + i;
      if (gr >= nrows) continue;
      int col = ct * 16 + lrow;
      qout[(size_t)gr * CD + col] = accq[ct][i];
      unsigned short* o = kvout + ((size_t)gr << 8);
      o[col] = f2bfbits(acck[ct][i]);
      o[CD + col] = f2bfbits(accv[ct][i]);
    }
  }
}

// ==== gate MFMA GEMM: gelu(agg)@Wa + ba, gated residual.
// do_final==0: -> h(f32) + h16(bf16).
// do_final==1 (last layer): h consumed only by the 128x2 output projection ->
// fuse it here (dot with Wfc + 16-lane shfl reduce), write ONLY the 2-wide
// output. Skips 77 MB of h/h16 writes + k_final's 51 MB re-read + a launch.
// The gated value o is bit-identical; only the final-dot f32 summation order
// differs from the old k_final (<< bf16 output quantum). ====
__global__ __launch_bounds__(256) void k_gemm_gate(
    const unsigned short* __restrict__ A, const unsigned short* __restrict__ BT,
    const float* __restrict__ bias, float* __restrict__ h,
    unsigned short* __restrict__ h16, const float* __restrict__ skip,
    const float* __restrict__ Wfc, const float* __restrict__ bfc,
    void* __restrict__ out, const int* __restrict__ flags,
    int do_final, int nrows) {
  const int w = threadIdx.x >> 6;
  const int l = threadIdx.x & 63;
  const int r0 = blockIdx.x * 64 + w * 16;
  if (r0 >= nrows) return;
  const int lrow = l & 15;
  const int quad = l >> 4;
  const int k0 = quad * 8;

  f32x4 acc[8];
#pragma unroll
  for (int ct = 0; ct < 8; ct++) {
    float b = bias[ct * 16 + lrow];
    acc[ct] = (f32x4){b, b, b, b};
  }
  int ar = r0 + lrow;
  if (ar >= nrows) ar = nrows - 1;
  const unsigned short* Ap = A + (size_t)ar * CD;
#pragma unroll
  for (int kc = 0; kc < 4; kc++) {
    bf16x8 af = *(const bf16x8*)(Ap + kc * 32 + k0);
#pragma unroll
    for (int ct = 0; ct < 8; ct++) {
      bf16x8 bfr = *(const bf16x8*)(BT + (size_t)(ct * 16 + lrow) * CD + kc * 32 + k0);
      acc[ct] = __builtin_amdgcn_mfma_f32_16x16x32_bf16(af, bfr, acc[ct], 0, 0, 0);
    }
  }
  float gg = 1.f / (1.f + __expf(-skip[0]));
  if (!do_final) {
#pragma unroll
    for (int ct = 0; ct < 8; ct++) {
#pragma unroll
      for (int i = 0; i < 4; i++) {
        int gr = r0 + quad * 4 + i;
        if (gr >= nrows) continue;
        size_t ix = (size_t)gr * CD + ct * 16 + lrow;
        float o = gg * acc[ct][i] + (1.f - gg) * h[ix];
        h[ix] = o;
        h16[ix] = f2bfbits(o);
      }
    }
  } else {
    float p0[4] = {0.f, 0.f, 0.f, 0.f};
    float p1[4] = {0.f, 0.f, 0.f, 0.f};
#pragma unroll
    for (int ct = 0; ct < 8; ct++) {
      float w0 = Wfc[(ct * 16 + lrow) * 2];
      float w1 = Wfc[(ct * 16 + lrow) * 2 + 1];
#pragma unroll
      for (int i = 0; i < 4; i++) {
        int gr = r0 + quad * 4 + i;
        if (gr >= nrows) continue;
        size_t ix = (size_t)gr * CD + ct * 16 + lrow;
        float o = gg * acc[ct][i] + (1.f - gg) * h[ix];
        p0[i] += o * w0;
        p1[i] += o * w1;
      }
    }
    // reduce across the 16 lanes (lrow) that share the same rows
#pragma unroll
    for (int off = 1; off <= 8; off <<= 1) {
#pragma unroll
      for (int i = 0; i < 4; i++) {
        p0[i] += __shfl_xor(p0[i], off);
        p1[i] += __shfl_xor(p1[i], off);
      }
    }
    if (lrow == 0) {
      int f32out = flags[0];
#pragma unroll
      for (int i = 0; i < 4; i++) {
        int gr = r0 + quad * 4 + i;
        if (gr >= nrows) continue;
        float o0 = p0[i] + bfc[0];
        float o1 = p1[i] + bfc[1];
        if (f32out) {
          ((float*)out)[(size_t)gr * 2] = o0;
          ((float*)out)[(size_t)gr * 2 + 1] = o1;
        } else {
          ((bf16*)out)[(size_t)gr * 2] = __float2bfloat16(o0);
          ((bf16*)out)[(size_t)gr * 2 + 1] = __float2bfloat16(o1);
        }
      }
    }
  }
}

// ==== CSR build ====
#define BTILE 4096
// fused: per-node degree atomics + LDS-aggregated coarse-bucket histogram
__global__ __launch_bounds__(256) void k_histb(
    const int* __restrict__ ei, int* __restrict__ deg, int* __restrict__ bcnt,
    const int* __restrict__ flags, int E, int Nn, int shift) {
  __shared__ int cnt[256];
  cnt[threadIdx.x] = 0;
  __syncthreads();
  const int t0 = blockIdx.x * BTILE;
  const int is64 = flags[1];
  for (int j = 0; j < 16; j++) {
    int i = t0 + threadIdx.x + j * 256;
    if (i < E) {
      int d = edge_idx(ei, (long)E + i, is64);
      if ((unsigned)d >= (unsigned)Nn) d = 0;
      atomicAdd(&deg[d], 1);
      atomicAdd(&cnt[d >> shift], 1);
    }
  }
  __syncthreads();
  int v = cnt[threadIdx.x];
  if (v > 0) atomicAdd(&bcnt[threadIdx.x], v);
}

__global__ void k_scan1(const int* __restrict__ deg, int* __restrict__ tmp,
                        int* __restrict__ bsum, int n) {
  __shared__ int sh[256];
  int i = blockIdx.x * 256 + threadIdx.x;
  int v = (i < n) ? deg[i] : 0;
  sh[threadIdx.x] = v;
  __syncthreads();
  for (int off = 1; off < 256; off <<= 1) {
    int t = (threadIdx.x >= off) ? sh[threadIdx.x - off] : 0;
    __syncthreads();
    sh[threadIdx.x] += t;
    __syncthreads();
  }
  if (i < n) tmp[i] = sh[threadIdx.x];
  if (threadIdx.x == 255) bsum[blockIdx.x] = sh[255];
}

__global__ void k_scan2(int* __restrict__ bsum, int nb) {
  __shared__ int sh[256];
  __shared__ int carry;
  if (threadIdx.x == 0) carry = 0;
  __syncthreads();
  for (int base = 0; base < nb; base += 256) {
    int i = base + threadIdx.x;
    int v = (i < nb) ? bsum[i] : 0;
    sh[threadIdx.x] = v;
    __syncthreads();
    for (int off = 1; off < 256; off <<= 1) {
      int t = (threadIdx.x >= off) ? sh[threadIdx.x - off] : 0;
      __syncthreads();
      sh[threadIdx.x] += t;
      __syncthreads();
    }
    if (i < nb) bsum[i] = sh[threadIdx.x] + carry;
    __syncthreads();
    if (threadIdx.x == 0) carry += sh[255];
    __syncthreads();
  }
}

__global__ void k_scan3(const int* __restrict__ tmp, const int* __restrict__ deg,
                        const int* __restrict__ bsum, int* __restrict__ rowptr,
                        int* __restrict__ fill, int n) {
  int i = blockIdx.x * 256 + threadIdx.x;
  if (i >= n) return;
  int off = (blockIdx.x > 0) ? bsum[blockIdx.x - 1] : 0;
  int excl = tmp[i] - deg[i] + off;
  rowptr[i] = excl;
  fill[i] = excl;
}

// exclusive scan of 256 bucket counts -> bbase; also init bfill
__global__ void k_bscan(const int* __restrict__ bcnt, int* __restrict__ bbase,
                        int* __restrict__ bfill) {
  __shared__ int sh[256];
  int t = threadIdx.x;
  int v = bcnt[t];
  sh[t] = v;
  __syncthreads();
  for (int off = 1; off < 256; off <<= 1) {
    int u = (t >= off) ? sh[t - off] : 0;
    __syncthreads();
    sh[t] += u;
    __syncthreads();
  }
  int excl = sh[t] - v;
  bbase[t] = excl;
  bfill[t] = excl;
}

// bin 4096-edge tiles into coarse buckets with clustered global writes
__global__ __launch_bounds__(256) void k_bin(
    const int* __restrict__ ei, int* __restrict__ bfill,
    int* __restrict__ ebs, int* __restrict__ ebd,
    const int* __restrict__ flags, int E, int Nn, int shift) {
  __shared__ int sS[BTILE];
  __shared__ int sD[BTILE];
  __shared__ int cnt[256], pref[256], base[256], lofs[256];
  const int t = threadIdx.x;
  cnt[t] = 0;
  lofs[t] = 0;
  __syncthreads();
  const int t0 = blockIdx.x * BTILE;
  const int is64 = flags[1];
  for (int j = 0; j < 16; j++) {
    int i = t0 + t + j * 256;
    if (i < E) {
      int d = edge_idx(ei, (long)E + i, is64);
      if ((unsigned)d >= (unsigned)Nn) d = 0;
      atomicAdd(&cnt[d >> shift], 1);
    }
  }
  __syncthreads();
  {
    int v = cnt[t];
    pref[t] = v;
    __syncthreads();
    for (int off = 1; off < 256; off <<= 1) {
      int u = (t >= off) ? pref[t - off] : 0;
      __syncthreads();
      pref[t] += u;
      __syncthreads();
    }
    int incl = pref[t];
    __syncthreads();
    pref[t] = incl - v;
    base[t] = (v > 0) ? atomicAdd(&bfill[t], v) : 0;
  }
  __syncthreads();
  for (int j = 0; j < 16; j++) {
    int i = t0 + t + j * 256;
    if (i < E) {
      int s = edge_idx(ei, (long)i, is64);
      int d = edge_idx(ei, (long)E + i, is64);
      if ((unsigned)s >= (unsigned)Nn) s = 0;
      if ((unsigned)d >= (unsigned)Nn) d = 0;
      int b = d >> shift;
      int p = pref[b] + atomicAdd(&lofs[b], 1);
      sS[p] = s;
      sD[p] = d;
    }
  }
  __syncthreads();
  int tot = E - t0;
  if (tot > BTILE) tot = BTILE;
  for (int j = 0; j < 16; j++) {
    int i = t + j * 256;
    if (i < tot) {
      int d = sD[i];
      int b = d >> shift;
      int gp = base[b] + (i - pref[b]);
      ebs[gp] = sS[i];
      ebd[gp] = d;
    }
  }
}

// final scatter within per-bucket csr window (L2-local)
__global__ void k_scatter2(const int* __restrict__ bbase, const int* __restrict__ bcnt,
                           const int* __restrict__ ebs, const int* __restrict__ ebd,
                           int* __restrict__ fill, int* __restrict__ csr_src) {
  int b = blockIdx.x >> 1, half = blockIdx.x & 1;
  int s0 = bbase[b], c = bcnt[b];
  int st = s0 + (half ? (c + 1) / 2 : 0);
  int en = s0 + (half ? c : (c + 1) / 2);
  for (int i = st + threadIdx.x; i < en; i += 256) {
    int s = ebs[i], d = ebd[i];
    int pos = atomicAdd(&fill[d], 1);
    csr_src[pos] = s;
  }
}

// ---- per-edge compute: unpack k/v, dot with q, exp, accumulate ----
__device__ __forceinline__ void edge_acc(uint4 ku, uint4 vu, float4 qa, float4 qb,
                                         float* __restrict__ acc, float& den) {
  float k0 = bfbits2f(ku.x & 0xffffu), k1 = bfbits2f(ku.x >> 16);
  float k2 = bfbits2f(ku.y & 0xffffu), k3 = bfbits2f(ku.y >> 16);
  float k4 = bfbits2f(ku.z & 0xffffu), k5 = bfbits2f(ku.z >> 16);
  float k6 = bfbits2f(ku.w & 0xffffu), k7 = bfbits2f(ku.w >> 16);
  float v0 = bfbits2f(vu.x & 0xffffu), v1 = bfbits2f(vu.x >> 16);
  float v2 = bfbits2f(vu.y & 0xffffu), v3 = bfbits2f(vu.y >> 16);
  float v4 = bfbits2f(vu.z & 0xffffu), v5 = bfbits2f(vu.z >> 16);
  float v6 = bfbits2f(vu.w & 0xffffu), v7 = bfbits2f(vu.w >> 16);
  float pd = qa.x * k0 + qa.y * k1 + qa.z * k2 + qa.w * k3 +
             qb.x * k4 + qb.y * k5 + qb.z * k6 + qb.w * k7;
  pd += __shfl_xor(pd, 1);
  pd += __shfl_xor(pd, 2);
  float ew = __expf(fminf(pd, 60.f));  // no max-sub: |logit| ~ O(1), safe
  acc[0] += ew * v0; acc[1] += ew * v1;
  acc[2] += ew * v2; acc[3] += ew * v3;
  acc[4] += ew * v4; acc[5] += ew * v5;
  acc[6] += ew * v6; acc[7] += ew * v7;
  den += ew;
}

// ==== fused attention, k/v interleaved bf16 (kv row = 512 B: k|v), NO online-max.
// 1 wave/node; 4 edge-slots x 16 lanes; lane j: dims 8j..8j+7 (head j>>2).
// p_rel/sqrt(D) folded into q. Rotated 2-pair software pipeline (kept from r2:
// neutral, not harmful). NOTE (r0-r2): gather path pinned at ~3.75 TB/s across
// three schedules/occupancies -> throughput ceiling of the random-256B gather
// pattern, not latency. Byte reduction (fp8 k / bf16 q) is the remaining lever
// here; deliberately untouched this round. ====
__global__ __launch_bounds__(256) void k_edge(
    const float* __restrict__ q, const unsigned short* __restrict__ kv,
    const int* __restrict__ rowptr, const int* __restrict__ deg,
    const int* __restrict__ csr_src, const float* __restrict__ p_rel,
    unsigned short* __restrict__ agg16, int N) {
  int n = (blockIdx.x * 256 + threadIdx.x) >> 6;
  if (n >= N) return;
  const int lane = threadIdx.x & 63;
  const int g = lane >> 4;
  const int j = lane & 15;
  const int start = rowptr[n];
  const int end = start + deg[n];
  const float prl = p_rel[j >> 2] * 0.17677669529663687f;  // 1/sqrt(32)
  float4 qa = *(const float4*)(q + (size_t)n * CD + 8 * j);
  float4 qb = *(const float4*)(q + (size_t)n * CD + 8 * j + 4);
  qa.x *= prl; qa.y *= prl; qa.z *= prl; qa.w *= prl;
  qb.x *= prl; qb.y *= prl; qb.z *= prl; qb.w *= prl;
  float den = 0.f;
  float acc[8] = {0.f, 0.f, 0.f, 0.f, 0.f, 0.f, 0.f, 0.f};
  int e = start + g;
  if (e < end) {
    const int last = end - 1;
    bool bok = (e + 4) < end;
    int sa = csr_src[e];
    int sb = csr_src[bok ? e + 4 : e];
    const unsigned short* pa = kv + ((size_t)sa << 8) + 8 * j;
    const unsigned short* pb = kv + ((size_t)sb << 8) + 8 * j;
    uint4 kua = *(const uint4*)pa;
    uint4 vua = *(const uint4*)(pa + CD);
    uint4 kub = *(const uint4*)pb;
    uint4 vub = *(const uint4*)(pb + CD);
    for (;;) {
      const int en = e + 8;
      // --- unconditional clamped prefetch of next pair ---
      int ea2 = (en < last) ? en : last;
      int eb2 = (en + 4 < last) ? en + 4 : last;
      int sa2 = csr_src[ea2];
      int sb2 = csr_src[eb2];
      const unsigned short* pa2 = kv + ((size_t)sa2 << 8) + 8 * j;
      const unsigned short* pb2 = kv + ((size_t)sb2 << 8) + 8 * j;
      uint4 kua2 = *(const uint4*)pa2;
      uint4 vua2 = *(const uint4*)(pa2 + CD);
      uint4 kub2 = *(const uint4*)pb2;
      uint4 vub2 = *(const uint4*)(pb2 + CD);
      __builtin_amdgcn_sched_barrier(0);
      // --- compute current pair (regs loaded one iteration ago) ---
      edge_acc(kua, vua, qa, qb, acc, den);
      if (bok) edge_acc(kub, vub, qa, qb, acc, den);
      if (en >= end) break;
      e = en;
      bok = (en + 4) < end;
      kua = kua2; vua = vua2; kub = kub2; vub = vub2;
    }
  }
#pragma unroll
  for (int off = 16; off <= 32; off <<= 1) {
    den += __shfl_xor(den, off);
#pragma unroll
    for (int i = 0; i < 8; i++) acc[i] += __shfl_xor(acc[i], off);
  }
  if (g == 0) {
    float inv = (den > 0.f) ? 1.f / den : 0.f;
    ushort4 o0, o1;
    o0.x = f2bfbits(gelu_f(acc[0] * inv)); o0.y = f2bfbits(gelu_f(acc[1] * inv));
    o0.z = f2bfbits(gelu_f(acc[2] * inv)); o0.w = f2bfbits(gelu_f(acc[3] * inv));
    o1.x = f2bfbits(gelu_f(acc[4] * inv)); o1.y = f2bfbits(gelu_f(acc[5] * inv));
    o1.z = f2bfbits(gelu_f(acc[6] * inv)); o1.w = f2bfbits(gelu_f(acc[7] * inv));
    *(ushort4*)(agg16 + (size_t)n * CD + 8 * j) = o0;
    *(ushort4*)(agg16 + (size_t)n * CD + 8 * j + 4) = o1;
  }
}

extern "C" void kernel_launch(void* const* d_in, const int* in_sizes, int n_in,
                              void* d_out, int out_size, void* d_ws, size_t ws_size,
                              hipStream_t stream) {
  const int* ei = (const int*)d_in[1];
  const int N = in_sizes[0] / CD;
  const int E = in_sizes[1] / 2;
  const size_t NC = (size_t)N * CD;
  const int nB = (N + 255) / 256;
  int shift = 0;
  while (((N - 1) >> shift) >= 256) shift++;  // 256 coarse buckets

  float* p = (float*)d_ws;
  float* hbuf = p;                                    // NC f32
  float* qbuf = p + NC;                               // NC f32
  float* cur = p + 2 * NC;
  unsigned short* hbuf16 = (unsigned short*)cur; cur += NC / 2;
  unsigned short* kvbuf16 = (unsigned short*)cur; cur += NC;  // N x 256 bf16 (k|v)
  unsigned short* agg16 = (unsigned short*)cur; cur += NC / 2;
  int* ip = (int*)cur;
  int* deg = ip;
  int* tmp = ip + N;
  int* rowptr = ip + 2 * N;
  int* fill = ip + 3 * N;
  int* bsum = ip + 4 * N;
  int* csr_src = ip + 4 * N + nB;
  int* bcnt = csr_src + E;     // 256
  int* bbase = bcnt + 256;     // 256
  int* bfill = bbase + 256;    // 256
  cur = (float*)(bfill + 256);
  unsigned short* wkeT = (unsigned short*)cur; cur += (size_t)LL * CD * CD / 2;
  unsigned short* wveT = (unsigned short*)cur; cur += (size_t)LL * CD * CD / 2;
  unsigned short* wqT = (unsigned short*)cur; cur += (size_t)LL * CD * CD / 2;
  unsigned short* waT = (unsigned short*)cur; cur += (size_t)LL * CD * CD / 2;
  float* bke = cur; cur += (size_t)LL * CD;
  float* bve = cur; cur += (size_t)LL * CD;
  float* pblock = cur;
  float* pWk = cur; cur += (size_t)LL * CD * CD;
  float* pbk = cur; cur += (size_t)LL * CD;
  float* pWq = cur; cur += (size_t)LL * CD * CD;
  float* pbq = cur; cur += (size_t)LL * CD;
  float* pWv = cur; cur += (size_t)LL * CD * CD;
  float* pbv = cur; cur += (size_t)LL * CD;
  float* par = cur; cur += (size_t)LL * HH * DH * DH;
  float* pmr = cur; cur += (size_t)LL * HH * DH * DH;
  float* ppr = cur; cur += (size_t)LL * HH;
  float* pWa = cur; cur += (size_t)LL * CD * CD;
  float* pba = cur; cur += (size_t)LL * CD;
  float* pskip = cur; cur += LL;
  float* pWfc = cur; cur += (size_t)CD * 2;
  float* pbfc = cur; cur += 2;
  int* flags = (int*)cur;

  // binned-edge staging aliases kvbuf16 (only used before layer loop)
  int* ebs = (int*)kvbuf16;      // E ints
  int* ebd = ebs + E;            // E ints

  k_detect<<<1, 128, 0, stream>>>(d_in[0], ei, flags);
  k_cvt_x<<<((int)NC + 255) / 256, 256, 0, stream>>>(d_in[0], hbuf, hbuf16,
                                                     (int)NC, flags);

  SegTab tab;
  const int sizes[NSEG] = {LL * CD * CD, LL * CD, LL * CD * CD, LL * CD,
                           LL * CD * CD, LL * CD, LL * HH * DH * DH,
                           LL * HH * DH * DH, LL * HH, LL * CD * CD, LL * CD,
                           LL, CD * 2, 2};
  const int srcIdx[NSEG] = {2, 3, 4, 5, 6, 7, 8, 9, 10, 11, 12, 13, 14, 15};
  int off = 0;
  for (int k = 0; k < NSEG; k++) {
    tab.src[k] = d_in[srcIdx[k]];
    tab.off[k] = off;
    off += sizes[k];
  }
  tab.total = off;
  k_cvt_params<<<(off + 255) / 256, 256, 0, stream>>>(tab, pblock, flags);

  k_eff<<<dim3(CD + 1, HH, LL * 2), DH, 0, stream>>>(pWk, pbk, pWv, pbv, par, pmr,
                                                     wkeT, bke, wveT, bve);
  k_wt<<<dim3(CD, 2 * LL), CD, 0, stream>>>(pWq, pWa, wqT, waT);

  // ---- CSR build with multisplit ----
  hipMemsetAsync(deg, 0, (size_t)N * sizeof(int), stream);
  hipMemsetAsync(bcnt, 0, 256 * sizeof(int), stream);
  k_histb<<<(E + BTILE - 1) / BTILE, 256, 0, stream>>>(ei, deg, bcnt, flags, E, N, shift);
  k_scan1<<<nB, 256, 0, stream>>>(deg, tmp, bsum, N);
  k_scan2<<<1, 256, 0, stream>>>(bsum, nB);
  k_scan3<<<nB, 256, 0, stream>>>(tmp, deg, bsum, rowptr, fill, N);
  k_bscan<<<1, 256, 0, stream>>>(bcnt, bbase, bfill);
  k_bin<<<(E + BTILE - 1) / BTILE, 256, 0, stream>>>(ei, bfill, ebs, ebd, flags,
                                                     E, N, shift);
  k_scatter2<<<512, 256, 0, stream>>>(bbase, bcnt, ebs, ebd, fill, csr_src);

  const int mfmaBlocks = (N + 63) / 64;
  for (int l = 0; l < LL; l++) {
    k_gemm_qkv3<<<mfmaBlocks, 256, 0, stream>>>(
        hbuf16,
        wqT + (size_t)l * CD * CD, wkeT + (size_t)l * CD * CD,
        wveT + (size_t)l * CD * CD,
        pbq + (size_t)l * CD, bke + (size_t)l * CD, bve + (size_t)l * CD,
        qbuf, kvbuf16, N);

    k_edge<<<(N + 3) / 4, 256, 0, stream>>>(qbuf, kvbuf16, rowptr, deg,
                                            csr_src, ppr + (size_t)l * HH, agg16, N);

    k_gemm_gate<<<mfmaBlocks, 256, 0, stream>>>(
        agg16, waT + (size_t)l * CD * CD, pba + (size_t)l * CD,
        hbuf, hbuf16, pskip + l, pWfc, pbfc, d_out, flags,
        (l == LL - 1) ? 1 : 0, N);
  }
}

// Round 4
// 818.859 us; speedup vs baseline: 1.0449x; 1.0449x over previous
//
#include <hip/hip_runtime.h>
#include <hip/hip_bf16.h>
#include <math.h>

#define CD 128
#define HH 4
#define DH 32
#define LL 2

using bf16 = __hip_bfloat16;
using bf16x8 = __attribute__((ext_vector_type(8))) short;  // 8 bf16 (4 VGPRs)
using f32x4 = __attribute__((ext_vector_type(4))) float;

__device__ __forceinline__ float bfbits2f(unsigned int s) {
  return __uint_as_float(s << 16);
}

__device__ __forceinline__ unsigned short f2bfbits(float f) {
  unsigned int u = __float_as_uint(f);
  unsigned int r = (u + 0x7fff + ((u >> 16) & 1)) >> 16;  // RNE
  return (unsigned short)r;
}

__device__ __forceinline__ float gelu_f(float x) {
  return 0.5f * x * (1.0f + erff(x * 0.70710678118654752f));
}

// ---- detect input formats: flags[0]=floats-are-f32, flags[1]=edge-index-is-i64 ----
__global__ void k_detect(const void* __restrict__ x, const int* __restrict__ ei,
                         int* __restrict__ flags) {
  __shared__ int cnt_f32, cnt_i32;
  if (threadIdx.x == 0) { cnt_f32 = 0; cnt_i32 = 0; }
  __syncthreads();
  int t = threadIdx.x;  // 128 threads
  unsigned short u = ((const unsigned short*)x)[2 * t];
  float v = bfbits2f((unsigned int)u);
  float av = fabsf(v);
  if (av != 0.f && (av > 1e8f || av < 1e-8f)) atomicAdd(&cnt_f32, 1);
  if (t < 64) {
    if (((const int*)ei)[2 * t + 1] != 0) atomicAdd(&cnt_i32, 1);
  }
  __syncthreads();
  if (threadIdx.x == 0) {
    flags[0] = (cnt_f32 > 8) ? 1 : 0;
    flags[1] = (cnt_i32 == 0) ? 1 : 0;
  }
}

#define NSEG 14
struct SegTab {
  const void* src[NSEG];
  int off[NSEG];
  int total;
};

__device__ __forceinline__ int edge_idx(const int* __restrict__ ei, long pos, int is64) {
  return is64 ? ei[2 * pos] : ei[pos];
}

#define BTILE 4096

// ==== FUSED pre-pass (launch-structure opt, r4): three INDEPENDENT roles in
// one dispatch, selected by blockIdx.x range. Overlaps cvt_x's streaming
// 100 MB with histb's atomic-bound phase; removes 2 launch gaps. Math of each
// role is bit-identical to the former separate kernels. cvt_x role is x8
// vectorized (G13; former scalar loads). ====
__global__ __launch_bounds__(256) void k_pre(
    const void* __restrict__ x, float* __restrict__ out,
    unsigned short* __restrict__ out16, long nc8,
    SegTab tab, float* __restrict__ pdst,
    const int* __restrict__ ei, int* __restrict__ deg, int* __restrict__ bcnt,
    int E, int Nn, int shift, const int* __restrict__ flags,
    int cvtB, int parB) {
  __shared__ int cnt[256];
  const int bx = blockIdx.x;
  if (bx < cvtB) {
    // --- cvt_x: x -> f32 out AND bf16 out16, 8 elems/thread ---
    long i8 = (long)bx * 256 + threadIdx.x;
    if (i8 >= nc8) return;
    long i = i8 * 8;
    float v0, v1, v2, v3, v4, v5, v6, v7;
    if (flags[0]) {
      float4 a = *(const float4*)((const float*)x + i);
      float4 b = *(const float4*)((const float*)x + i + 4);
      v0 = a.x; v1 = a.y; v2 = a.z; v3 = a.w;
      v4 = b.x; v5 = b.y; v6 = b.z; v7 = b.w;
    } else {
      ushort4 a = *(const ushort4*)((const unsigned short*)x + i);
      ushort4 b = *(const ushort4*)((const unsigned short*)x + i + 4);
      v0 = bfbits2f(a.x); v1 = bfbits2f(a.y); v2 = bfbits2f(a.z); v3 = bfbits2f(a.w);
      v4 = bfbits2f(b.x); v5 = bfbits2f(b.y); v6 = bfbits2f(b.z); v7 = bfbits2f(b.w);
    }
    *(float4*)(out + i) = (float4){v0, v1, v2, v3};
    *(float4*)(out + i + 4) = (float4){v4, v5, v6, v7};
    ushort4 o0, o1;
    o0.x = f2bfbits(v0); o0.y = f2bfbits(v1); o0.z = f2bfbits(v2); o0.w = f2bfbits(v3);
    o1.x = f2bfbits(v4); o1.y = f2bfbits(v5); o1.z = f2bfbits(v6); o1.w = f2bfbits(v7);
    *(ushort4*)(out16 + i) = o0;
    *(ushort4*)(out16 + i + 4) = o1;
  } else if (bx < cvtB + parB) {
    // --- cvt_params: all parameter tensors -> contiguous f32 block ---
    int i = (bx - cvtB) * 256 + threadIdx.x;
    if (i >= tab.total) return;
    int seg = 0;
#pragma unroll
    for (int k = 1; k < NSEG; k++)
      if (i >= tab.off[k]) seg = k;
    int j = i - tab.off[seg];
    const void* src = tab.src[seg];
    pdst[i] = flags[0] ? ((const float*)src)[j]
                       : bfbits2f((unsigned int)((const unsigned short*)src)[j]);
  } else {
    // --- histb: per-node degree atomics + coarse-bucket histogram ---
    cnt[threadIdx.x] = 0;
    __syncthreads();
    const int t0 = (bx - cvtB - parB) * BTILE;
    const int is64 = flags[1];
    for (int j = 0; j < 16; j++) {
      int i = t0 + threadIdx.x + j * 256;
      if (i < E) {
        int d = edge_idx(ei, (long)E + i, is64);
        if ((unsigned)d >= (unsigned)Nn) d = 0;
        atomicAdd(&deg[d], 1);
        atomicAdd(&cnt[d >> shift], 1);
      }
    }
    __syncthreads();
    int v = cnt[threadIdx.x];
    if (v > 0) atomicAdd(&bcnt[threadIdx.x], v);
  }
}

// ==== FUSED stage 2: {eff (fold relation transforms), wt (transpose Wq/Wa),
// scan1 (per-256-block prefix of deg)} — all depend only on k_pre outputs,
// mutually independent. Former k_eff/k_wt grids flattened to 256-thread
// blocks; inner math identical. ====
__global__ __launch_bounds__(256) void k_w1(
    const float* __restrict__ pWk, const float* __restrict__ pbk,
    const float* __restrict__ pWv, const float* __restrict__ pbv,
    const float* __restrict__ par, const float* __restrict__ pmr,
    unsigned short* __restrict__ wkeT, float* __restrict__ bke,
    unsigned short* __restrict__ wveT, float* __restrict__ bve,
    const float* __restrict__ pWq, const float* __restrict__ pWa,
    unsigned short* __restrict__ wqT, unsigned short* __restrict__ waT,
    const int* __restrict__ deg, int* __restrict__ tmp, int* __restrict__ bsum,
    int n, int effB, int wtB) {
  __shared__ int sh[256];
  const int bx = blockIdx.x;
  if (bx < effB) {
    int i = bx * 256 + threadIdx.x;
    const int total = LL * 2 * (CD + 1) * HH * DH;
    if (i >= total) return;
    int e = i & 31;
    int h = (i >> 5) & 3;
    int c = (i >> 7) % (CD + 1);
    int z = (i >> 7) / (CD + 1);
    int l = z >> 1, which = z & 1;
    const float* W = (which ? pWv : pWk) + (size_t)l * CD * CD;
    const float* B = (which ? pbv : pbk) + (size_t)l * CD;
    const float* R = (which ? pmr : par) + (size_t)l * HH * DH * DH + h * DH * DH;
    unsigned short* WoT = (which ? wveT : wkeT) + (size_t)l * CD * CD;
    float* Bo = (which ? bve : bke) + (size_t)l * CD;
    float acc = 0.f;
    if (c < CD) {
#pragma unroll
      for (int d = 0; d < DH; d++) acc += W[c * CD + h * DH + d] * R[d * DH + e];
      WoT[(size_t)(h * DH + e) * CD + c] = f2bfbits(acc);
    } else {
#pragma unroll
      for (int d = 0; d < DH; d++) acc += B[h * DH + d] * R[d * DH + e];
      Bo[h * DH + e] = acc;
    }
  } else if (bx < effB + wtB) {
    int i = (bx - effB) * 256 + threadIdx.x;  // < LL*2*CD*CD exactly
    int cin = i & 127;
    int cout = (i >> 7) & 127;
    int z = i >> 14;
    int l = z >> 1, which = z & 1;
    const float* W = (which ? pWa : pWq) + (size_t)l * CD * CD;
    unsigned short* WT = (which ? waT : wqT) + (size_t)l * CD * CD;
    WT[(size_t)cout * CD + cin] = f2bfbits(W[(size_t)cin * CD + cout]);
  } else {
    const int b = bx - effB - wtB;
    int i = b * 256 + threadIdx.x;
    int v = (i < n) ? deg[i] : 0;
    sh[threadIdx.x] = v;
    __syncthreads();
    for (int off = 1; off < 256; off <<= 1) {
      int t = (threadIdx.x >= off) ? sh[threadIdx.x - off] : 0;
      __syncthreads();
      sh[threadIdx.x] += t;
      __syncthreads();
    }
    if (i < n) tmp[i] = sh[threadIdx.x];
    if (threadIdx.x == 255) bsum[b] = sh[255];
  }
}

// ==== FUSED stage 3: {scan2 (serial block-sum scan), bscan (bucket scan)} —
// both single-block, independent. ====
__global__ __launch_bounds__(256) void k_s2(
    int* __restrict__ bsum, int nb, const int* __restrict__ bcnt,
    int* __restrict__ bbase, int* __restrict__ bfill) {
  __shared__ int sh[256];
  __shared__ int carry;
  if (blockIdx.x == 0) {
    if (threadIdx.x == 0) carry = 0;
    __syncthreads();
    for (int base = 0; base < nb; base += 256) {
      int i = base + threadIdx.x;
      int v = (i < nb) ? bsum[i] : 0;
      sh[threadIdx.x] = v;
      __syncthreads();
      for (int off = 1; off < 256; off <<= 1) {
        int t = (threadIdx.x >= off) ? sh[threadIdx.x - off] : 0;
        __syncthreads();
        sh[threadIdx.x] += t;
        __syncthreads();
      }
      if (i < nb) bsum[i] = sh[threadIdx.x] + carry;
      __syncthreads();
      if (threadIdx.x == 0) carry += sh[255];
      __syncthreads();
    }
  } else {
    int t = threadIdx.x;
    int v = bcnt[t];
    sh[t] = v;
    __syncthreads();
    for (int off = 1; off < 256; off <<= 1) {
      int u = (t >= off) ? sh[t - off] : 0;
      __syncthreads();
      sh[t] += u;
      __syncthreads();
    }
    int excl = sh[t] - v;
    bbase[t] = excl;
    bfill[t] = excl;
  }
}

// ==== FUSED stage 4: {scan3 (rowptr/fill), bin (bucket the edges)} —
// scan3 needs bsum (k_s2 role 0), bin needs bbase/bfill (k_s2 role 1);
// mutually independent. ====
__global__ __launch_bounds__(256) void k_s3bin(
    const int* __restrict__ tmp, const int* __restrict__ deg,
    const int* __restrict__ bsum, int* __restrict__ rowptr,
    int* __restrict__ fill, int n, int nB,
    const int* __restrict__ ei, int* __restrict__ bfill,
    int* __restrict__ ebs, int* __restrict__ ebd,
    const int* __restrict__ flags, int E, int Nn, int shift) {
  __shared__ int sS[BTILE];
  __shared__ int sD[BTILE];
  __shared__ int cnt[256], pref[256], base[256], lofs[256];
  const int bx = blockIdx.x;
  if (bx < nB) {
    int i = bx * 256 + threadIdx.x;
    if (i >= n) return;
    int off = (bx > 0) ? bsum[bx - 1] : 0;
    int excl = tmp[i] - deg[i] + off;
    rowptr[i] = excl;
    fill[i] = excl;
    return;
  }
  const int t = threadIdx.x;
  cnt[t] = 0;
  lofs[t] = 0;
  __syncthreads();
  const int t0 = (bx - nB) * BTILE;
  const int is64 = flags[1];
  for (int j = 0; j < 16; j++) {
    int i = t0 + t + j * 256;
    if (i < E) {
      int d = edge_idx(ei, (long)E + i, is64);
      if ((unsigned)d >= (unsigned)Nn) d = 0;
      atomicAdd(&cnt[d >> shift], 1);
    }
  }
  __syncthreads();
  {
    int v = cnt[t];
    pref[t] = v;
    __syncthreads();
    for (int off = 1; off < 256; off <<= 1) {
      int u = (t >= off) ? pref[t - off] : 0;
      __syncthreads();
      pref[t] += u;
      __syncthreads();
    }
    int incl = pref[t];
    __syncthreads();
    pref[t] = incl - v;
    base[t] = (v > 0) ? atomicAdd(&bfill[t], v) : 0;
  }
  __syncthreads();
  for (int j = 0; j < 16; j++) {
    int i = t0 + t + j * 256;
    if (i < E) {
      int s = edge_idx(ei, (long)i, is64);
      int d = edge_idx(ei, (long)E + i, is64);
      if ((unsigned)s >= (unsigned)Nn) s = 0;
      if ((unsigned)d >= (unsigned)Nn) d = 0;
      int b = d >> shift;
      int p = pref[b] + atomicAdd(&lofs[b], 1);
      sS[p] = s;
      sD[p] = d;
    }
  }
  __syncthreads();
  int tot = E - t0;
  if (tot > BTILE) tot = BTILE;
  for (int j = 0; j < 16; j++) {
    int i = t + j * 256;
    if (i < tot) {
      int d = sD[i];
      int b = d >> shift;
      int gp = base[b] + (i - pref[b]);
      ebs[gp] = sS[i];
      ebd[gp] = d;
    }
  }
}

// final scatter within per-bucket csr window (L2-local)
__global__ void k_scatter2(const int* __restrict__ bbase, const int* __restrict__ bcnt,
                           const int* __restrict__ ebs, const int* __restrict__ ebd,
                           int* __restrict__ fill, int* __restrict__ csr_src) {
  int b = blockIdx.x >> 1, half = blockIdx.x & 1;
  int s0 = bbase[b], c = bcnt[b];
  int st = s0 + (half ? (c + 1) / 2 : 0);
  int en = s0 + (half ? c : (c + 1) / 2);
  for (int i = st + threadIdx.x; i < en; i += 256) {
    int s = ebs[i], d = ebd[i];
    int pos = atomicAdd(&fill[d], 1);
    csr_src[pos] = s;
  }
}

// ==== fused q/k/v MFMA GEMM, zero-LDS; grid.y selects projection (r2 version:
// r3's single-pass fusion REGRESSED +20us — acc VGPR x3 cut occupancy, and the
// "saved" traffic was L3-resident anyway).
// y=0: q (f32 out); y=1: k -> kv[row][0:128]; y=2: v -> kv[row][128:256]. ====
__global__ __launch_bounds__(256) void k_gemm_qkv(
    const unsigned short* __restrict__ A,
    const unsigned short* __restrict__ wq, const unsigned short* __restrict__ wk,
    const unsigned short* __restrict__ wv,
    const float* __restrict__ bq, const float* __restrict__ bk,
    const float* __restrict__ bv,
    float* __restrict__ qout, unsigned short* __restrict__ kvout, int nrows) {
  const int which = blockIdx.y;
  const unsigned short* BT = (which == 0) ? wq : (which == 1) ? wk : wv;
  const float* bias = (which == 0) ? bq : (which == 1) ? bk : bv;
  const int w = threadIdx.x >> 6;
  const int l = threadIdx.x & 63;
  const int r0 = blockIdx.x * 64 + w * 16;
  if (r0 >= nrows) return;
  const int lrow = l & 15;
  const int quad = l >> 4;
  const int k0 = quad * 8;

  f32x4 acc[8];
#pragma unroll
  for (int ct = 0; ct < 8; ct++) {
    float b = bias[ct * 16 + lrow];
    acc[ct] = (f32x4){b, b, b, b};
  }
  int ar = r0 + lrow;
  if (ar >= nrows) ar = nrows - 1;
  const unsigned short* Ap = A + (size_t)ar * CD;
#pragma unroll
  for (int kc = 0; kc < 4; kc++) {
    bf16x8 af = *(const bf16x8*)(Ap + kc * 32 + k0);
#pragma unroll
    for (int ct = 0; ct < 8; ct++) {
      bf16x8 bfr = *(const bf16x8*)(BT + (size_t)(ct * 16 + lrow) * CD + kc * 32 + k0);
      acc[ct] = __builtin_amdgcn_mfma_f32_16x16x32_bf16(af, bfr, acc[ct], 0, 0, 0);
    }
  }
#pragma unroll
  for (int ct = 0; ct < 8; ct++) {
#pragma unroll
    for (int i = 0; i < 4; i++) {
      int gr = r0 + quad * 4 + i;
      if (gr >= nrows) continue;
      int col = ct * 16 + lrow;
      float val = acc[ct][i];
      if (which == 0) {
        qout[(size_t)gr * CD + col] = val;
      } else {
        unsigned short* o = kvout + ((size_t)gr << 8) + ((which == 2) ? CD : 0);
        o[col] = f2bfbits(val);
      }
    }
  }
}

// ==== gate MFMA GEMM (r2 version): gelu(agg)@Wa + ba, gated residual ->
// h(f32) + h16(bf16). (r3's fused final projection regressed; reverted.) ====
__global__ __launch_bounds__(256) void k_gemm_gate(
    const unsigned short* __restrict__ A, const unsigned short* __restrict__ BT,
    const float* __restrict__ bias, float* __restrict__ h,
    unsigned short* __restrict__ h16, const float* __restrict__ skip, int nrows) {
  const int w = threadIdx.x >> 6;
  const int l = threadIdx.x & 63;
  const int r0 = blockIdx.x * 64 + w * 16;
  if (r0 >= nrows) return;
  const int lrow = l & 15;
  const int quad = l >> 4;
  const int k0 = quad * 8;

  f32x4 acc[8];
#pragma unroll
  for (int ct = 0; ct < 8; ct++) {
    float b = bias[ct * 16 + lrow];
    acc[ct] = (f32x4){b, b, b, b};
  }
  int ar = r0 + lrow;
  if (ar >= nrows) ar = nrows - 1;
  const unsigned short* Ap = A + (size_t)ar * CD;
#pragma unroll
  for (int kc = 0; kc < 4; kc++) {
    bf16x8 af = *(const bf16x8*)(Ap + kc * 32 + k0);
#pragma unroll
    for (int ct = 0; ct < 8; ct++) {
      bf16x8 bfr = *(const bf16x8*)(BT + (size_t)(ct * 16 + lrow) * CD + kc * 32 + k0);
      acc[ct] = __builtin_amdgcn_mfma_f32_16x16x32_bf16(af, bfr, acc[ct], 0, 0, 0);
    }
  }
  float gg = 1.f / (1.f + __expf(-skip[0]));
#pragma unroll
  for (int ct = 0; ct < 8; ct++) {
#pragma unroll
    for (int i = 0; i < 4; i++) {
      int gr = r0 + quad * 4 + i;
      if (gr >= nrows) continue;
      size_t ix = (size_t)gr * CD + ct * 16 + lrow;
      float o = gg * acc[ct][i] + (1.f - gg) * h[ix];
      h[ix] = o;
      h16[ix] = f2bfbits(o);
    }
  }
}

// ---- per-edge compute: unpack k/v, dot with q, exp, accumulate ----
__device__ __forceinline__ void edge_acc(uint4 ku, uint4 vu, float4 qa, float4 qb,
                                         float* __restrict__ acc, float& den) {
  float k0 = bfbits2f(ku.x & 0xffffu), k1 = bfbits2f(ku.x >> 16);
  float k2 = bfbits2f(ku.y & 0xffffu), k3 = bfbits2f(ku.y >> 16);
  float k4 = bfbits2f(ku.z & 0xffffu), k5 = bfbits2f(ku.z >> 16);
  float k6 = bfbits2f(ku.w & 0xffffu), k7 = bfbits2f(ku.w >> 16);
  float v0 = bfbits2f(vu.x & 0xffffu), v1 = bfbits2f(vu.x >> 16);
  float v2 = bfbits2f(vu.y & 0xffffu), v3 = bfbits2f(vu.y >> 16);
  float v4 = bfbits2f(vu.z & 0xffffu), v5 = bfbits2f(vu.z >> 16);
  float v6 = bfbits2f(vu.w & 0xffffu), v7 = bfbits2f(vu.w >> 16);
  float pd = qa.x * k0 + qa.y * k1 + qa.z * k2 + qa.w * k3 +
             qb.x * k4 + qb.y * k5 + qb.z * k6 + qb.w * k7;
  pd += __shfl_xor(pd, 1);
  pd += __shfl_xor(pd, 2);
  float ew = __expf(fminf(pd, 60.f));  // no max-sub: |logit| ~ O(1), safe
  acc[0] += ew * v0; acc[1] += ew * v1;
  acc[2] += ew * v2; acc[3] += ew * v3;
  acc[4] += ew * v4; acc[5] += ew * v5;
  acc[6] += ew * v6; acc[7] += ew * v7;
  den += ew;
}

// ==== fused attention, k/v interleaved bf16 (kv row = 512 B: k|v), NO online-max.
// 1 wave/node; 4 edge-slots x 16 lanes; lane j: dims 8j..8j+7 (head j>>2).
// p_rel/sqrt(D) folded into q. Rotated 2-pair software pipeline.
// NOTE (r0-r3): gather path pinned at ~3.75 TB/s across three schedules and
// occupancies 68-77% -> throughput ceiling of the random-256B gather pattern.
// Left untouched this round. ====
__global__ __launch_bounds__(256) void k_edge(
    const float* __restrict__ q, const unsigned short* __restrict__ kv,
    const int* __restrict__ rowptr, const int* __restrict__ deg,
    const int* __restrict__ csr_src, const float* __restrict__ p_rel,
    unsigned short* __restrict__ agg16, int N) {
  int n = (blockIdx.x * 256 + threadIdx.x) >> 6;
  if (n >= N) return;
  const int lane = threadIdx.x & 63;
  const int g = lane >> 4;
  const int j = lane & 15;
  const int start = rowptr[n];
  const int end = start + deg[n];
  const float prl = p_rel[j >> 2] * 0.17677669529663687f;  // 1/sqrt(32)
  float4 qa = *(const float4*)(q + (size_t)n * CD + 8 * j);
  float4 qb = *(const float4*)(q + (size_t)n * CD + 8 * j + 4);
  qa.x *= prl; qa.y *= prl; qa.z *= prl; qa.w *= prl;
  qb.x *= prl; qb.y *= prl; qb.z *= prl; qb.w *= prl;
  float den = 0.f;
  float acc[8] = {0.f, 0.f, 0.f, 0.f, 0.f, 0.f, 0.f, 0.f};
  int e = start + g;
  if (e < end) {
    const int last = end - 1;
    bool bok = (e + 4) < end;
    int sa = csr_src[e];
    int sb = csr_src[bok ? e + 4 : e];
    const unsigned short* pa = kv + ((size_t)sa << 8) + 8 * j;
    const unsigned short* pb = kv + ((size_t)sb << 8) + 8 * j;
    uint4 kua = *(const uint4*)pa;
    uint4 vua = *(const uint4*)(pa + CD);
    uint4 kub = *(const uint4*)pb;
    uint4 vub = *(const uint4*)(pb + CD);
    for (;;) {
      const int en = e + 8;
      int ea2 = (en < last) ? en : last;
      int eb2 = (en + 4 < last) ? en + 4 : last;
      int sa2 = csr_src[ea2];
      int sb2 = csr_src[eb2];
      const unsigned short* pa2 = kv + ((size_t)sa2 << 8) + 8 * j;
      const unsigned short* pb2 = kv + ((size_t)sb2 << 8) + 8 * j;
      uint4 kua2 = *(const uint4*)pa2;
      uint4 vua2 = *(const uint4*)(pa2 + CD);
      uint4 kub2 = *(const uint4*)pb2;
      uint4 vub2 = *(const uint4*)(pb2 + CD);
      __builtin_amdgcn_sched_barrier(0);
      edge_acc(kua, vua, qa, qb, acc, den);
      if (bok) edge_acc(kub, vub, qa, qb, acc, den);
      if (en >= end) break;
      e = en;
      bok = (en + 4) < end;
      kua = kua2; vua = vua2; kub = kub2; vub = vub2;
    }
  }
#pragma unroll
  for (int off = 16; off <= 32; off <<= 1) {
    den += __shfl_xor(den, off);
#pragma unroll
    for (int i = 0; i < 8; i++) acc[i] += __shfl_xor(acc[i], off);
  }
  if (g == 0) {
    float inv = (den > 0.f) ? 1.f / den : 0.f;
    ushort4 o0, o1;
    o0.x = f2bfbits(gelu_f(acc[0] * inv)); o0.y = f2bfbits(gelu_f(acc[1] * inv));
    o0.z = f2bfbits(gelu_f(acc[2] * inv)); o0.w = f2bfbits(gelu_f(acc[3] * inv));
    o1.x = f2bfbits(gelu_f(acc[4] * inv)); o1.y = f2bfbits(gelu_f(acc[5] * inv));
    o1.z = f2bfbits(gelu_f(acc[6] * inv)); o1.w = f2bfbits(gelu_f(acc[7] * inv));
    *(ushort4*)(agg16 + (size_t)n * CD + 8 * j) = o0;
    *(ushort4*)(agg16 + (size_t)n * CD + 8 * j + 4) = o1;
  }
}

// ---- out[n,0:2] = h[n,:] @ Wfc + bfc; f32 out if flags[0] else bf16 ----
__global__ __launch_bounds__(256) void k_final(const float* __restrict__ h,
                                               const float* __restrict__ Wfc,
                                               const float* __restrict__ bfc,
                                               void* __restrict__ out,
                                               const int* __restrict__ flags, int N) {
  int g = (blockIdx.x * 256 + threadIdx.x) >> 5;
  int lane = threadIdx.x & 31;
  if (g >= N) return;
  const float* hr = h + (size_t)g * CD;
  float a0 = 0.f, a1 = 0.f;
#pragma unroll
  for (int j = 0; j < 4; j++) {
    float hv = hr[lane + 32 * j];
    a0 += hv * Wfc[(lane + 32 * j) * 2];
    a1 += hv * Wfc[(lane + 32 * j) * 2 + 1];
  }
#pragma unroll
  for (int off = 16; off; off >>= 1) {
    a0 += __shfl_xor(a0, off);
    a1 += __shfl_xor(a1, off);
  }
  if (lane == 0) {
    float o0 = a0 + bfc[0];
    float o1 = a1 + bfc[1];
    if (flags[0]) {
      ((float*)out)[(size_t)g * 2] = o0;
      ((float*)out)[(size_t)g * 2 + 1] = o1;
    } else {
      ((bf16*)out)[(size_t)g * 2] = __float2bfloat16(o0);
      ((bf16*)out)[(size_t)g * 2 + 1] = __float2bfloat16(o1);
    }
  }
}

extern "C" void kernel_launch(void* const* d_in, const int* in_sizes, int n_in,
                              void* d_out, int out_size, void* d_ws, size_t ws_size,
                              hipStream_t stream) {
  const int* ei = (const int*)d_in[1];
  const int N = in_sizes[0] / CD;
  const int E = in_sizes[1] / 2;
  const size_t NC = (size_t)N * CD;
  const int nB = (N + 255) / 256;
  int shift = 0;
  while (((N - 1) >> shift) >= 256) shift++;  // 256 coarse buckets

  float* p = (float*)d_ws;
  float* hbuf = p;                                    // NC f32
  float* qbuf = p + NC;                               // NC f32
  float* cur = p + 2 * NC;
  unsigned short* hbuf16 = (unsigned short*)cur; cur += NC / 2;
  unsigned short* kvbuf16 = (unsigned short*)cur; cur += NC;  // N x 256 bf16 (k|v)
  unsigned short* agg16 = (unsigned short*)cur; cur += NC / 2;
  int* ip = (int*)cur;
  int* deg = ip;
  int* tmp = ip + N;
  int* rowptr = ip + 2 * N;
  int* fill = ip + 3 * N;
  int* bsum = ip + 4 * N;
  int* csr_src = ip + 4 * N + nB;
  int* bcnt = csr_src + E;     // 256
  int* bbase = bcnt + 256;     // 256
  int* bfill = bbase + 256;    // 256
  cur = (float*)(bfill + 256);
  unsigned short* wkeT = (unsigned short*)cur; cur += (size_t)LL * CD * CD / 2;
  unsigned short* wveT = (unsigned short*)cur; cur += (size_t)LL * CD * CD / 2;
  unsigned short* wqT = (unsigned short*)cur; cur += (size_t)LL * CD * CD / 2;
  unsigned short* waT = (unsigned short*)cur; cur += (size_t)LL * CD * CD / 2;
  float* bke = cur; cur += (size_t)LL * CD;
  float* bve = cur; cur += (size_t)LL * CD;
  float* pblock = cur;
  float* pWk = cur; cur += (size_t)LL * CD * CD;
  float* pbk = cur; cur += (size_t)LL * CD;
  float* pWq = cur; cur += (size_t)LL * CD * CD;
  float* pbq = cur; cur += (size_t)LL * CD;
  float* pWv = cur; cur += (size_t)LL * CD * CD;
  float* pbv = cur; cur += (size_t)LL * CD;
  float* par = cur; cur += (size_t)LL * HH * DH * DH;
  float* pmr = cur; cur += (size_t)LL * HH * DH * DH;
  float* ppr = cur; cur += (size_t)LL * HH;
  float* pWa = cur; cur += (size_t)LL * CD * CD;
  float* pba = cur; cur += (size_t)LL * CD;
  float* pskip = cur; cur += LL;
  float* pWfc = cur; cur += (size_t)CD * 2;
  float* pbfc = cur; cur += 2;
  int* flags = (int*)cur;

  // binned-edge staging aliases kvbuf16 (only used before layer loop)
  int* ebs = (int*)kvbuf16;      // E ints
  int* ebd = ebs + E;            // E ints

  SegTab tab;
  const int sizes[NSEG] = {LL * CD * CD, LL * CD, LL * CD * CD, LL * CD,
                           LL * CD * CD, LL * CD, LL * HH * DH * DH,
                           LL * HH * DH * DH, LL * HH, LL * CD * CD, LL * CD,
                           LL, CD * 2, 2};
  const int srcIdx[NSEG] = {2, 3, 4, 5, 6, 7, 8, 9, 10, 11, 12, 13, 14, 15};
  int off = 0;
  for (int k = 0; k < NSEG; k++) {
    tab.src[k] = d_in[srcIdx[k]];
    tab.off[k] = off;
    off += sizes[k];
  }
  tab.total = off;

  hipMemsetAsync(deg, 0, (size_t)N * sizeof(int), stream);
  hipMemsetAsync(bcnt, 0, 256 * sizeof(int), stream);
  k_detect<<<1, 128, 0, stream>>>(d_in[0], ei, flags);

  const long nc8 = (long)(NC / 8);
  const int cvtB = (int)((nc8 + 255) / 256);
  const int parB = (tab.total + 255) / 256;
  const int histB = (E + BTILE - 1) / BTILE;
  k_pre<<<cvtB + parB + histB, 256, 0, stream>>>(
      d_in[0], hbuf, hbuf16, nc8, tab, pblock, ei, deg, bcnt, E, N, shift,
      flags, cvtB, parB);

  const int effB = (LL * 2 * (CD + 1) * HH * DH + 255) / 256;
  const int wtB = (LL * 2 * CD * CD) / 256;
  k_w1<<<effB + wtB + nB, 256, 0, stream>>>(
      pWk, pbk, pWv, pbv, par, pmr, wkeT, bke, wveT, bve,
      pWq, pWa, wqT, waT, deg, tmp, bsum, N, effB, wtB);

  k_s2<<<2, 256, 0, stream>>>(bsum, nB, bcnt, bbase, bfill);
  k_s3bin<<<nB + histB, 256, 0, stream>>>(tmp, deg, bsum, rowptr, fill, N, nB,
                                          ei, bfill, ebs, ebd, flags, E, N, shift);
  k_scatter2<<<512, 256, 0, stream>>>(bbase, bcnt, ebs, ebd, fill, csr_src);

  const int mfmaBlocks = (N + 63) / 64;
  for (int l = 0; l < LL; l++) {
    k_gemm_qkv<<<dim3(mfmaBlocks, 3), 256, 0, stream>>>(
        hbuf16,
        wqT + (size_t)l * CD * CD, wkeT + (size_t)l * CD * CD,
        wveT + (size_t)l * CD * CD,
        pbq + (size_t)l * CD, bke + (size_t)l * CD, bve + (size_t)l * CD,
        qbuf, kvbuf16, N);

    k_edge<<<(N + 3) / 4, 256, 0, stream>>>(qbuf, kvbuf16, rowptr, deg,
                                            csr_src, ppr + (size_t)l * HH, agg16, N);

    k_gemm_gate<<<mfmaBlocks, 256, 0, stream>>>(
        agg16, waT + (size_t)l * CD * CD, pba + (size_t)l * CD,
        hbuf, hbuf16, pskip + l, N);
  }
  k_final<<<(N + 7) / 8, 256, 0, stream>>>(hbuf, pWfc, pbfc, d_out, flags, N);
}

// Round 5
// 803.506 us; speedup vs baseline: 1.0648x; 1.0191x over previous
//
#include <hip/hip_runtime.h>
#include <hip/hip_bf16.h>
#include <math.h>

#define CD 128
#define HH 4
#define DH 32
#define LL 2

using bf16 = __hip_bfloat16;
using bf16x8 = __attribute__((ext_vector_type(8))) short;  // 8 bf16 (4 VGPRs)
using f32x4 = __attribute__((ext_vector_type(4))) float;

__device__ __forceinline__ float bfbits2f(unsigned int s) {
  return __uint_as_float(s << 16);
}

__device__ __forceinline__ unsigned short f2bfbits(float f) {
  unsigned int u = __float_as_uint(f);
  unsigned int r = (u + 0x7fff + ((u >> 16) & 1)) >> 16;  // RNE
  return (unsigned short)r;
}

__device__ __forceinline__ float gelu_f(float x) {
  return 0.5f * x * (1.0f + erff(x * 0.70710678118654752f));
}

// ---- detect input formats: flags[0]=floats-are-f32, flags[1]=edge-index-is-i64 ----
__global__ void k_detect(const void* __restrict__ x, const int* __restrict__ ei,
                         int* __restrict__ flags) {
  __shared__ int cnt_f32, cnt_i32;
  if (threadIdx.x == 0) { cnt_f32 = 0; cnt_i32 = 0; }
  __syncthreads();
  int t = threadIdx.x;  // 128 threads
  unsigned short u = ((const unsigned short*)x)[2 * t];
  float v = bfbits2f((unsigned int)u);
  float av = fabsf(v);
  if (av != 0.f && (av > 1e8f || av < 1e-8f)) atomicAdd(&cnt_f32, 1);
  if (t < 64) {
    if (((const int*)ei)[2 * t + 1] != 0) atomicAdd(&cnt_i32, 1);
  }
  __syncthreads();
  if (threadIdx.x == 0) {
    flags[0] = (cnt_f32 > 8) ? 1 : 0;
    flags[1] = (cnt_i32 == 0) ? 1 : 0;
  }
}

#define NSEG 14
struct SegTab {
  const void* src[NSEG];
  int off[NSEG];
  int total;
};

__device__ __forceinline__ int edge_idx(const int* __restrict__ ei, long pos, int is64) {
  return is64 ? ei[2 * pos] : ei[pos];
}

#define BTILE 4096

// ==== FUSED pre-pass (r5: cvt-x role DELETED — x is consumed directly by
// qkv-l0 / gate-l0 with in-register conversion; the 102 MB cvt pass was pure
// overhead). Remaining roles: {cvt_params, histb}. ====
__global__ __launch_bounds__(256) void k_pre(
    SegTab tab, float* __restrict__ pdst,
    const int* __restrict__ ei, int* __restrict__ deg, int* __restrict__ bcnt,
    int E, int Nn, int shift, const int* __restrict__ flags, int parB) {
  __shared__ int cnt[256];
  const int bx = blockIdx.x;
  if (bx < parB) {
    // --- cvt_params: all parameter tensors -> contiguous f32 block ---
    int i = bx * 256 + threadIdx.x;
    if (i >= tab.total) return;
    int seg = 0;
#pragma unroll
    for (int k = 1; k < NSEG; k++)
      if (i >= tab.off[k]) seg = k;
    int j = i - tab.off[seg];
    const void* src = tab.src[seg];
    pdst[i] = flags[0] ? ((const float*)src)[j]
                       : bfbits2f((unsigned int)((const unsigned short*)src)[j]);
  } else {
    // --- histb: per-node degree atomics + coarse-bucket histogram ---
    cnt[threadIdx.x] = 0;
    __syncthreads();
    const int t0 = (bx - parB) * BTILE;
    const int is64 = flags[1];
    for (int j = 0; j < 16; j++) {
      int i = t0 + threadIdx.x + j * 256;
      if (i < E) {
        int d = edge_idx(ei, (long)E + i, is64);
        if ((unsigned)d >= (unsigned)Nn) d = 0;
        atomicAdd(&deg[d], 1);
        atomicAdd(&cnt[d >> shift], 1);
      }
    }
    __syncthreads();
    int v = cnt[threadIdx.x];
    if (v > 0) atomicAdd(&bcnt[threadIdx.x], v);
  }
}

// ==== FUSED stage 2: {eff, wt, scan1} (r4, unchanged) ====
__global__ __launch_bounds__(256) void k_w1(
    const float* __restrict__ pWk, const float* __restrict__ pbk,
    const float* __restrict__ pWv, const float* __restrict__ pbv,
    const float* __restrict__ par, const float* __restrict__ pmr,
    unsigned short* __restrict__ wkeT, float* __restrict__ bke,
    unsigned short* __restrict__ wveT, float* __restrict__ bve,
    const float* __restrict__ pWq, const float* __restrict__ pWa,
    unsigned short* __restrict__ wqT, unsigned short* __restrict__ waT,
    const int* __restrict__ deg, int* __restrict__ tmp, int* __restrict__ bsum,
    int n, int effB, int wtB) {
  __shared__ int sh[256];
  const int bx = blockIdx.x;
  if (bx < effB) {
    int i = bx * 256 + threadIdx.x;
    const int total = LL * 2 * (CD + 1) * HH * DH;
    if (i >= total) return;
    int e = i & 31;
    int h = (i >> 5) & 3;
    int c = (i >> 7) % (CD + 1);
    int z = (i >> 7) / (CD + 1);
    int l = z >> 1, which = z & 1;
    const float* W = (which ? pWv : pWk) + (size_t)l * CD * CD;
    const float* B = (which ? pbv : pbk) + (size_t)l * CD;
    const float* R = (which ? pmr : par) + (size_t)l * HH * DH * DH + h * DH * DH;
    unsigned short* WoT = (which ? wveT : wkeT) + (size_t)l * CD * CD;
    float* Bo = (which ? bve : bke) + (size_t)l * CD;
    float acc = 0.f;
    if (c < CD) {
#pragma unroll
      for (int d = 0; d < DH; d++) acc += W[c * CD + h * DH + d] * R[d * DH + e];
      WoT[(size_t)(h * DH + e) * CD + c] = f2bfbits(acc);
    } else {
#pragma unroll
      for (int d = 0; d < DH; d++) acc += B[h * DH + d] * R[d * DH + e];
      Bo[h * DH + e] = acc;
    }
  } else if (bx < effB + wtB) {
    int i = (bx - effB) * 256 + threadIdx.x;  // < LL*2*CD*CD exactly
    int cin = i & 127;
    int cout = (i >> 7) & 127;
    int z = i >> 14;
    int l = z >> 1, which = z & 1;
    const float* W = (which ? pWa : pWq) + (size_t)l * CD * CD;
    unsigned short* WT = (which ? waT : wqT) + (size_t)l * CD * CD;
    WT[(size_t)cout * CD + cin] = f2bfbits(W[(size_t)cin * CD + cout]);
  } else {
    const int b = bx - effB - wtB;
    int i = b * 256 + threadIdx.x;
    int v = (i < n) ? deg[i] : 0;
    sh[threadIdx.x] = v;
    __syncthreads();
    for (int off = 1; off < 256; off <<= 1) {
      int t = (threadIdx.x >= off) ? sh[threadIdx.x - off] : 0;
      __syncthreads();
      sh[threadIdx.x] += t;
      __syncthreads();
    }
    if (i < n) tmp[i] = sh[threadIdx.x];
    if (threadIdx.x == 255) bsum[b] = sh[255];
  }
}

// ==== FUSED stage 3: {scan2, bscan} (r4, unchanged) ====
__global__ __launch_bounds__(256) void k_s2(
    int* __restrict__ bsum, int nb, const int* __restrict__ bcnt,
    int* __restrict__ bbase, int* __restrict__ bfill) {
  __shared__ int sh[256];
  __shared__ int carry;
  if (blockIdx.x == 0) {
    if (threadIdx.x == 0) carry = 0;
    __syncthreads();
    for (int base = 0; base < nb; base += 256) {
      int i = base + threadIdx.x;
      int v = (i < nb) ? bsum[i] : 0;
      sh[threadIdx.x] = v;
      __syncthreads();
      for (int off = 1; off < 256; off <<= 1) {
        int t = (threadIdx.x >= off) ? sh[threadIdx.x - off] : 0;
        __syncthreads();
        sh[threadIdx.x] += t;
        __syncthreads();
      }
      if (i < nb) bsum[i] = sh[threadIdx.x] + carry;
      __syncthreads();
      if (threadIdx.x == 0) carry += sh[255];
      __syncthreads();
    }
  } else {
    int t = threadIdx.x;
    int v = bcnt[t];
    sh[t] = v;
    __syncthreads();
    for (int off = 1; off < 256; off <<= 1) {
      int u = (t >= off) ? sh[t - off] : 0;
      __syncthreads();
      sh[t] += u;
      __syncthreads();
    }
    int excl = sh[t] - v;
    bbase[t] = excl;
    bfill[t] = excl;
  }
}

// ==== FUSED stage 4: {scan3, bin} (r4, unchanged) ====
__global__ __launch_bounds__(256) void k_s3bin(
    const int* __restrict__ tmp, const int* __restrict__ deg,
    const int* __restrict__ bsum, int* __restrict__ rowptr,
    int* __restrict__ fill, int n, int nB,
    const int* __restrict__ ei, int* __restrict__ bfill,
    int* __restrict__ ebs, int* __restrict__ ebd,
    const int* __restrict__ flags, int E, int Nn, int shift) {
  __shared__ int sS[BTILE];
  __shared__ int sD[BTILE];
  __shared__ int cnt[256], pref[256], base[256], lofs[256];
  const int bx = blockIdx.x;
  if (bx < nB) {
    int i = bx * 256 + threadIdx.x;
    if (i >= n) return;
    int off = (bx > 0) ? bsum[bx - 1] : 0;
    int excl = tmp[i] - deg[i] + off;
    rowptr[i] = excl;
    fill[i] = excl;
    return;
  }
  const int t = threadIdx.x;
  cnt[t] = 0;
  lofs[t] = 0;
  __syncthreads();
  const int t0 = (bx - nB) * BTILE;
  const int is64 = flags[1];
  for (int j = 0; j < 16; j++) {
    int i = t0 + t + j * 256;
    if (i < E) {
      int d = edge_idx(ei, (long)E + i, is64);
      if ((unsigned)d >= (unsigned)Nn) d = 0;
      atomicAdd(&cnt[d >> shift], 1);
    }
  }
  __syncthreads();
  {
    int v = cnt[t];
    pref[t] = v;
    __syncthreads();
    for (int off = 1; off < 256; off <<= 1) {
      int u = (t >= off) ? pref[t - off] : 0;
      __syncthreads();
      pref[t] += u;
      __syncthreads();
    }
    int incl = pref[t];
    __syncthreads();
    pref[t] = incl - v;
    base[t] = (v > 0) ? atomicAdd(&bfill[t], v) : 0;
  }
  __syncthreads();
  for (int j = 0; j < 16; j++) {
    int i = t0 + t + j * 256;
    if (i < E) {
      int s = edge_idx(ei, (long)i, is64);
      int d = edge_idx(ei, (long)E + i, is64);
      if ((unsigned)s >= (unsigned)Nn) s = 0;
      if ((unsigned)d >= (unsigned)Nn) d = 0;
      int b = d >> shift;
      int p = pref[b] + atomicAdd(&lofs[b], 1);
      sS[p] = s;
      sD[p] = d;
    }
  }
  __syncthreads();
  int tot = E - t0;
  if (tot > BTILE) tot = BTILE;
  for (int j = 0; j < 16; j++) {
    int i = t + j * 256;
    if (i < tot) {
      int d = sD[i];
      int b = d >> shift;
      int gp = base[b] + (i - pref[b]);
      ebs[gp] = sS[i];
      ebd[gp] = d;
    }
  }
}

// final scatter within per-bucket csr window (L2-local)
__global__ void k_scatter2(const int* __restrict__ bbase, const int* __restrict__ bcnt,
                           const int* __restrict__ ebs, const int* __restrict__ ebd,
                           int* __restrict__ fill, int* __restrict__ csr_src) {
  int b = blockIdx.x >> 1, half = blockIdx.x & 1;
  int s0 = bbase[b], c = bcnt[b];
  int st = s0 + (half ? (c + 1) / 2 : 0);
  int en = s0 + (half ? c : (c + 1) / 2);
  for (int i = st + threadIdx.x; i < en; i += 256) {
    int s = ebs[i], d = ebd[i];
    int pos = atomicAdd(&fill[d], 1);
    csr_src[pos] = s;
  }
}

// ==== fused q/k/v MFMA GEMM, zero-LDS; grid.y selects projection.
// r5: A may be the raw input x (a_is_x=1): bf16 input -> reinterpret (bits
// identical to old hbuf16); f32 input -> in-register f2bfbits (same RNE,
// bit-identical fragments). Eliminates the cvt-x pass + hbuf16 for layer 0. ====
__global__ __launch_bounds__(256) void k_gemm_qkv(
    const void* __restrict__ Araw, int a_is_x, const int* __restrict__ flags,
    const unsigned short* __restrict__ wq, const unsigned short* __restrict__ wk,
    const unsigned short* __restrict__ wv,
    const float* __restrict__ bq, const float* __restrict__ bk,
    const float* __restrict__ bv,
    float* __restrict__ qout, unsigned short* __restrict__ kvout, int nrows) {
  const int which = blockIdx.y;
  const unsigned short* BT = (which == 0) ? wq : (which == 1) ? wk : wv;
  const float* bias = (which == 0) ? bq : (which == 1) ? bk : bv;
  const int w = threadIdx.x >> 6;
  const int l = threadIdx.x & 63;
  const int r0 = blockIdx.x * 64 + w * 16;
  if (r0 >= nrows) return;
  const int lrow = l & 15;
  const int quad = l >> 4;
  const int k0 = quad * 8;
  const int ax_f32 = a_is_x ? flags[0] : 0;

  f32x4 acc[8];
#pragma unroll
  for (int ct = 0; ct < 8; ct++) {
    float b = bias[ct * 16 + lrow];
    acc[ct] = (f32x4){b, b, b, b};
  }
  int ar = r0 + lrow;
  if (ar >= nrows) ar = nrows - 1;
#pragma unroll
  for (int kc = 0; kc < 4; kc++) {
    bf16x8 af;
    if (ax_f32) {
      const float* Af = (const float*)Araw + (size_t)ar * CD + kc * 32 + k0;
      float4 a = *(const float4*)Af;
      float4 b = *(const float4*)(Af + 4);
      af[0] = (short)f2bfbits(a.x); af[1] = (short)f2bfbits(a.y);
      af[2] = (short)f2bfbits(a.z); af[3] = (short)f2bfbits(a.w);
      af[4] = (short)f2bfbits(b.x); af[5] = (short)f2bfbits(b.y);
      af[6] = (short)f2bfbits(b.z); af[7] = (short)f2bfbits(b.w);
    } else {
      af = *(const bf16x8*)((const unsigned short*)Araw + (size_t)ar * CD + kc * 32 + k0);
    }
#pragma unroll
    for (int ct = 0; ct < 8; ct++) {
      bf16x8 bfr = *(const bf16x8*)(BT + (size_t)(ct * 16 + lrow) * CD + kc * 32 + k0);
      acc[ct] = __builtin_amdgcn_mfma_f32_16x16x32_bf16(af, bfr, acc[ct], 0, 0, 0);
    }
  }
#pragma unroll
  for (int ct = 0; ct < 8; ct++) {
#pragma unroll
    for (int i = 0; i < 4; i++) {
      int gr = r0 + quad * 4 + i;
      if (gr >= nrows) continue;
      int col = ct * 16 + lrow;
      float val = acc[ct][i];
      if (which == 0) {
        qout[(size_t)gr * CD + col] = val;
      } else {
        unsigned short* o = kvout + ((size_t)gr << 8) + ((which == 2) ? CD : 0);
        o[col] = f2bfbits(val);
      }
    }
  }
}

// ==== gate MFMA GEMM: gelu(agg)@Wa + ba, gated residual.
// r5: residual source selectable — use_x=1 (layer 0) reads raw x (exact in
// both input formats, kills the hbuf pre-pass); use_x=0 reads h f32.
// do_final=1 (last layer): h consumed only by the 128x2 output projection ->
// fuse it (dot with Wfc + 16-lane shfl reduce), write ONLY the 2-wide output.
// Skips 77 MB h/h16 writes + k_final's 51 MB re-read + a launch. Gated value
// o is bit-identical; only final-dot f32 sum order differs (r3: passed). ====
__global__ __launch_bounds__(256) void k_gemm_gate(
    const unsigned short* __restrict__ A, const unsigned short* __restrict__ BT,
    const float* __restrict__ bias, const void* __restrict__ xres,
    float* __restrict__ h, unsigned short* __restrict__ h16,
    const float* __restrict__ skip,
    const float* __restrict__ Wfc, const float* __restrict__ bfc,
    void* __restrict__ out, const int* __restrict__ flags,
    int use_x, int do_final, int nrows) {
  const int w = threadIdx.x >> 6;
  const int l = threadIdx.x & 63;
  const int r0 = blockIdx.x * 64 + w * 16;
  if (r0 >= nrows) return;
  const int lrow = l & 15;
  const int quad = l >> 4;
  const int k0 = quad * 8;
  const int xf32 = flags[0];

  f32x4 acc[8];
#pragma unroll
  for (int ct = 0; ct < 8; ct++) {
    float b = bias[ct * 16 + lrow];
    acc[ct] = (f32x4){b, b, b, b};
  }
  int ar = r0 + lrow;
  if (ar >= nrows) ar = nrows - 1;
  const unsigned short* Ap = A + (size_t)ar * CD;
#pragma unroll
  for (int kc = 0; kc < 4; kc++) {
    bf16x8 af = *(const bf16x8*)(Ap + kc * 32 + k0);
#pragma unroll
    for (int ct = 0; ct < 8; ct++) {
      bf16x8 bfr = *(const bf16x8*)(BT + (size_t)(ct * 16 + lrow) * CD + kc * 32 + k0);
      acc[ct] = __builtin_amdgcn_mfma_f32_16x16x32_bf16(af, bfr, acc[ct], 0, 0, 0);
    }
  }
  float gg = 1.f / (1.f + __expf(-skip[0]));
  if (!do_final) {
#pragma unroll
    for (int ct = 0; ct < 8; ct++) {
#pragma unroll
      for (int i = 0; i < 4; i++) {
        int gr = r0 + quad * 4 + i;
        if (gr >= nrows) continue;
        size_t ix = (size_t)gr * CD + ct * 16 + lrow;
        float hres;
        if (use_x) {
          hres = xf32 ? ((const float*)xres)[ix]
                      : bfbits2f((unsigned int)((const unsigned short*)xres)[ix]);
        } else {
          hres = h[ix];
        }
        float o = gg * acc[ct][i] + (1.f - gg) * hres;
        h[ix] = o;
        h16[ix] = f2bfbits(o);
      }
    }
  } else {
    float p0[4] = {0.f, 0.f, 0.f, 0.f};
    float p1[4] = {0.f, 0.f, 0.f, 0.f};
#pragma unroll
    for (int ct = 0; ct < 8; ct++) {
      float w0 = Wfc[(ct * 16 + lrow) * 2];
      float w1 = Wfc[(ct * 16 + lrow) * 2 + 1];
#pragma unroll
      for (int i = 0; i < 4; i++) {
        int gr = r0 + quad * 4 + i;
        if (gr >= nrows) continue;
        size_t ix = (size_t)gr * CD + ct * 16 + lrow;
        float hres;
        if (use_x) {
          hres = xf32 ? ((const float*)xres)[ix]
                      : bfbits2f((unsigned int)((const unsigned short*)xres)[ix]);
        } else {
          hres = h[ix];
        }
        float o = gg * acc[ct][i] + (1.f - gg) * hres;
        p0[i] += o * w0;
        p1[i] += o * w1;
      }
    }
#pragma unroll
    for (int off = 1; off <= 8; off <<= 1) {
#pragma unroll
      for (int i = 0; i < 4; i++) {
        p0[i] += __shfl_xor(p0[i], off);
        p1[i] += __shfl_xor(p1[i], off);
      }
    }
    if (lrow == 0) {
#pragma unroll
      for (int i = 0; i < 4; i++) {
        int gr = r0 + quad * 4 + i;
        if (gr >= nrows) continue;
        float o0 = p0[i] + bfc[0];
        float o1 = p1[i] + bfc[1];
        if (xf32) {
          ((float*)out)[(size_t)gr * 2] = o0;
          ((float*)out)[(size_t)gr * 2 + 1] = o1;
        } else {
          ((bf16*)out)[(size_t)gr * 2] = __float2bfloat16(o0);
          ((bf16*)out)[(size_t)gr * 2 + 1] = __float2bfloat16(o1);
        }
      }
    }
  }
}

// ---- per-edge compute: unpack k/v, dot with q, exp, accumulate ----
__device__ __forceinline__ void edge_acc(uint4 ku, uint4 vu, float4 qa, float4 qb,
                                         float* __restrict__ acc, float& den) {
  float k0 = bfbits2f(ku.x & 0xffffu), k1 = bfbits2f(ku.x >> 16);
  float k2 = bfbits2f(ku.y & 0xffffu), k3 = bfbits2f(ku.y >> 16);
  float k4 = bfbits2f(ku.z & 0xffffu), k5 = bfbits2f(ku.z >> 16);
  float k6 = bfbits2f(ku.w & 0xffffu), k7 = bfbits2f(ku.w >> 16);
  float v0 = bfbits2f(vu.x & 0xffffu), v1 = bfbits2f(vu.x >> 16);
  float v2 = bfbits2f(vu.y & 0xffffu), v3 = bfbits2f(vu.y >> 16);
  float v4 = bfbits2f(vu.z & 0xffffu), v5 = bfbits2f(vu.z >> 16);
  float v6 = bfbits2f(vu.w & 0xffffu), v7 = bfbits2f(vu.w >> 16);
  float pd = qa.x * k0 + qa.y * k1 + qa.z * k2 + qa.w * k3 +
             qb.x * k4 + qb.y * k5 + qb.z * k6 + qb.w * k7;
  pd += __shfl_xor(pd, 1);
  pd += __shfl_xor(pd, 2);
  float ew = __expf(fminf(pd, 60.f));  // no max-sub: |logit| ~ O(1), safe
  acc[0] += ew * v0; acc[1] += ew * v1;
  acc[2] += ew * v2; acc[3] += ew * v3;
  acc[4] += ew * v4; acc[5] += ew * v5;
  acc[6] += ew * v6; acc[7] += ew * v7;
  den += ew;
}

// ==== fused attention (unchanged from r4; pinned at the random-256B-gather
// throughput ceiling ~3.75 TB/s across 3 schedules / occupancies 67-77%). ====
__global__ __launch_bounds__(256) void k_edge(
    const float* __restrict__ q, const unsigned short* __restrict__ kv,
    const int* __restrict__ rowptr, const int* __restrict__ deg,
    const int* __restrict__ csr_src, const float* __restrict__ p_rel,
    unsigned short* __restrict__ agg16, int N) {
  int n = (blockIdx.x * 256 + threadIdx.x) >> 6;
  if (n >= N) return;
  const int lane = threadIdx.x & 63;
  const int g = lane >> 4;
  const int j = lane & 15;
  const int start = rowptr[n];
  const int end = start + deg[n];
  const float prl = p_rel[j >> 2] * 0.17677669529663687f;  // 1/sqrt(32)
  float4 qa = *(const float4*)(q + (size_t)n * CD + 8 * j);
  float4 qb = *(const float4*)(q + (size_t)n * CD + 8 * j + 4);
  qa.x *= prl; qa.y *= prl; qa.z *= prl; qa.w *= prl;
  qb.x *= prl; qb.y *= prl; qb.z *= prl; qb.w *= prl;
  float den = 0.f;
  float acc[8] = {0.f, 0.f, 0.f, 0.f, 0.f, 0.f, 0.f, 0.f};
  int e = start + g;
  if (e < end) {
    const int last = end - 1;
    bool bok = (e + 4) < end;
    int sa = csr_src[e];
    int sb = csr_src[bok ? e + 4 : e];
    const unsigned short* pa = kv + ((size_t)sa << 8) + 8 * j;
    const unsigned short* pb = kv + ((size_t)sb << 8) + 8 * j;
    uint4 kua = *(const uint4*)pa;
    uint4 vua = *(const uint4*)(pa + CD);
    uint4 kub = *(const uint4*)pb;
    uint4 vub = *(const uint4*)(pb + CD);
    for (;;) {
      const int en = e + 8;
      int ea2 = (en < last) ? en : last;
      int eb2 = (en + 4 < last) ? en + 4 : last;
      int sa2 = csr_src[ea2];
      int sb2 = csr_src[eb2];
      const unsigned short* pa2 = kv + ((size_t)sa2 << 8) + 8 * j;
      const unsigned short* pb2 = kv + ((size_t)sb2 << 8) + 8 * j;
      uint4 kua2 = *(const uint4*)pa2;
      uint4 vua2 = *(const uint4*)(pa2 + CD);
      uint4 kub2 = *(const uint4*)pb2;
      uint4 vub2 = *(const uint4*)(pb2 + CD);
      __builtin_amdgcn_sched_barrier(0);
      edge_acc(kua, vua, qa, qb, acc, den);
      if (bok) edge_acc(kub, vub, qa, qb, acc, den);
      if (en >= end) break;
      e = en;
      bok = (en + 4) < end;
      kua = kua2; vua = vua2; kub = kub2; vub = vub2;
    }
  }
#pragma unroll
  for (int off = 16; off <= 32; off <<= 1) {
    den += __shfl_xor(den, off);
#pragma unroll
    for (int i = 0; i < 8; i++) acc[i] += __shfl_xor(acc[i], off);
  }
  if (g == 0) {
    float inv = (den > 0.f) ? 1.f / den : 0.f;
    ushort4 o0, o1;
    o0.x = f2bfbits(gelu_f(acc[0] * inv)); o0.y = f2bfbits(gelu_f(acc[1] * inv));
    o0.z = f2bfbits(gelu_f(acc[2] * inv)); o0.w = f2bfbits(gelu_f(acc[3] * inv));
    o1.x = f2bfbits(gelu_f(acc[4] * inv)); o1.y = f2bfbits(gelu_f(acc[5] * inv));
    o1.z = f2bfbits(gelu_f(acc[6] * inv)); o1.w = f2bfbits(gelu_f(acc[7] * inv));
    *(ushort4*)(agg16 + (size_t)n * CD + 8 * j) = o0;
    *(ushort4*)(agg16 + (size_t)n * CD + 8 * j + 4) = o1;
  }
}

extern "C" void kernel_launch(void* const* d_in, const int* in_sizes, int n_in,
                              void* d_out, int out_size, void* d_ws, size_t ws_size,
                              hipStream_t stream) {
  const int* ei = (const int*)d_in[1];
  const int N = in_sizes[0] / CD;
  const int E = in_sizes[1] / 2;
  const size_t NC = (size_t)N * CD;
  const int nB = (N + 255) / 256;
  int shift = 0;
  while (((N - 1) >> shift) >= 256) shift++;  // 256 coarse buckets

  float* p = (float*)d_ws;
  float* hbuf = p;                                    // NC f32 (h1 storage)
  float* qbuf = p + NC;                               // NC f32
  float* cur = p + 2 * NC;
  unsigned short* hbuf16 = (unsigned short*)cur; cur += NC / 2;  // h1 bf16
  unsigned short* kvbuf16 = (unsigned short*)cur; cur += NC;  // N x 256 bf16 (k|v)
  unsigned short* agg16 = (unsigned short*)cur; cur += NC / 2;
  int* ip = (int*)cur;
  int* deg = ip;
  int* tmp = ip + N;
  int* rowptr = ip + 2 * N;
  int* fill = ip + 3 * N;
  int* bsum = ip + 4 * N;
  int* csr_src = ip + 4 * N + nB;
  int* bcnt = csr_src + E;     // 256
  int* bbase = bcnt + 256;     // 256
  int* bfill = bbase + 256;    // 256
  cur = (float*)(bfill + 256);
  unsigned short* wkeT = (unsigned short*)cur; cur += (size_t)LL * CD * CD / 2;
  unsigned short* wveT = (unsigned short*)cur; cur += (size_t)LL * CD * CD / 2;
  unsigned short* wqT = (unsigned short*)cur; cur += (size_t)LL * CD * CD / 2;
  unsigned short* waT = (unsigned short*)cur; cur += (size_t)LL * CD * CD / 2;
  float* bke = cur; cur += (size_t)LL * CD;
  float* bve = cur; cur += (size_t)LL * CD;
  float* pblock = cur;
  float* pWk = cur; cur += (size_t)LL * CD * CD;
  float* pbk = cur; cur += (size_t)LL * CD;
  float* pWq = cur; cur += (size_t)LL * CD * CD;
  float* pbq = cur; cur += (size_t)LL * CD;
  float* pWv = cur; cur += (size_t)LL * CD * CD;
  float* pbv = cur; cur += (size_t)LL * CD;
  float* par = cur; cur += (size_t)LL * HH * DH * DH;
  float* pmr = cur; cur += (size_t)LL * HH * DH * DH;
  float* ppr = cur; cur += (size_t)LL * HH;
  float* pWa = cur; cur += (size_t)LL * CD * CD;
  float* pba = cur; cur += (size_t)LL * CD;
  float* pskip = cur; cur += LL;
  float* pWfc = cur; cur += (size_t)CD * 2;
  float* pbfc = cur; cur += 2;
  int* flags = (int*)cur;

  // binned-edge staging aliases kvbuf16 (only used before layer loop)
  int* ebs = (int*)kvbuf16;      // E ints
  int* ebd = ebs + E;            // E ints

  SegTab tab;
  const int sizes[NSEG] = {LL * CD * CD, LL * CD, LL * CD * CD, LL * CD,
                           LL * CD * CD, LL * CD, LL * HH * DH * DH,
                           LL * HH * DH * DH, LL * HH, LL * CD * CD, LL * CD,
                           LL, CD * 2, 2};
  const int srcIdx[NSEG] = {2, 3, 4, 5, 6, 7, 8, 9, 10, 11, 12, 13, 14, 15};
  int off = 0;
  for (int k = 0; k < NSEG; k++) {
    tab.src[k] = d_in[srcIdx[k]];
    tab.off[k] = off;
    off += sizes[k];
  }
  tab.total = off;

  hipMemsetAsync(deg, 0, (size_t)N * sizeof(int), stream);
  hipMemsetAsync(bcnt, 0, 256 * sizeof(int), stream);
  k_detect<<<1, 128, 0, stream>>>(d_in[0], ei, flags);

  const int parB = (tab.total + 255) / 256;
  const int histB = (E + BTILE - 1) / BTILE;
  k_pre<<<parB + histB, 256, 0, stream>>>(tab, pblock, ei, deg, bcnt, E, N,
                                          shift, flags, parB);

  const int effB = (LL * 2 * (CD + 1) * HH * DH + 255) / 256;
  const int wtB = (LL * 2 * CD * CD) / 256;
  k_w1<<<effB + wtB + nB, 256, 0, stream>>>(
      pWk, pbk, pWv, pbv, par, pmr, wkeT, bke, wveT, bve,
      pWq, pWa, wqT, waT, deg, tmp, bsum, N, effB, wtB);

  k_s2<<<2, 256, 0, stream>>>(bsum, nB, bcnt, bbase, bfill);
  k_s3bin<<<nB + histB, 256, 0, stream>>>(tmp, deg, bsum, rowptr, fill, N, nB,
                                          ei, bfill, ebs, ebd, flags, E, N, shift);
  k_scatter2<<<512, 256, 0, stream>>>(bbase, bcnt, ebs, ebd, fill, csr_src);

  const int mfmaBlocks = (N + 63) / 64;
  for (int l = 0; l < LL; l++) {
    k_gemm_qkv<<<dim3(mfmaBlocks, 3), 256, 0, stream>>>(
        (l == 0) ? d_in[0] : (const void*)hbuf16, (l == 0) ? 1 : 0, flags,
        wqT + (size_t)l * CD * CD, wkeT + (size_t)l * CD * CD,
        wveT + (size_t)l * CD * CD,
        pbq + (size_t)l * CD, bke + (size_t)l * CD, bve + (size_t)l * CD,
        qbuf, kvbuf16, N);

    k_edge<<<(N + 3) / 4, 256, 0, stream>>>(qbuf, kvbuf16, rowptr, deg,
                                            csr_src, ppr + (size_t)l * HH, agg16, N);

    k_gemm_gate<<<mfmaBlocks, 256, 0, stream>>>(
        agg16, waT + (size_t)l * CD * CD, pba + (size_t)l * CD,
        d_in[0], hbuf, hbuf16, pskip + l, pWfc, pbfc, d_out, flags,
        (l == 0) ? 1 : 0, (l == LL - 1) ? 1 : 0, N);
  }
}

// Round 7
// 780.209 us; speedup vs baseline: 1.0966x; 1.0299x over previous
//
#include <hip/hip_runtime.h>
#include <hip/hip_bf16.h>
#include <math.h>

#define CD 128
#define HH 4
#define DH 32
#define LL 2

using bf16 = __hip_bfloat16;
using bf16x8 = __attribute__((ext_vector_type(8))) short;  // 8 bf16 (4 VGPRs)
using f32x4 = __attribute__((ext_vector_type(4))) float;

__device__ __forceinline__ float bfbits2f(unsigned int s) {
  return __uint_as_float(s << 16);
}

__device__ __forceinline__ unsigned short f2bfbits(float f) {
  unsigned int u = __float_as_uint(f);
  unsigned int r = (u + 0x7fff + ((u >> 16) & 1)) >> 16;  // RNE
  return (unsigned short)r;
}

__device__ __forceinline__ float gelu_f(float x) {
  return 0.5f * x * (1.0f + erff(x * 0.70710678118654752f));
}

// ---- detect input formats: flags[0]=floats-are-f32, flags[1]=edge-index-is-i64 ----
__global__ void k_detect(const void* __restrict__ x, const int* __restrict__ ei,
                         int* __restrict__ flags) {
  __shared__ int cnt_f32, cnt_i32;
  if (threadIdx.x == 0) { cnt_f32 = 0; cnt_i32 = 0; }
  __syncthreads();
  int t = threadIdx.x;  // 128 threads
  unsigned short u = ((const unsigned short*)x)[2 * t];
  float v = bfbits2f((unsigned int)u);
  float av = fabsf(v);
  if (av != 0.f && (av > 1e8f || av < 1e-8f)) atomicAdd(&cnt_f32, 1);
  if (t < 64) {
    if (((const int*)ei)[2 * t + 1] != 0) atomicAdd(&cnt_i32, 1);
  }
  __syncthreads();
  if (threadIdx.x == 0) {
    flags[0] = (cnt_f32 > 8) ? 1 : 0;
    flags[1] = (cnt_i32 == 0) ? 1 : 0;
  }
}

#define NSEG 14
struct SegTab {
  const void* src[NSEG];
  int off[NSEG];
  int total;
};

__device__ __forceinline__ int edge_idx(const int* __restrict__ ei, long pos, int is64) {
  return is64 ? ei[2 * pos] : ei[pos];
}

#define BTILE 4096

// ==== FUSED pre-pass: {cvt_params, histb} (r5) ====
__global__ __launch_bounds__(256) void k_pre(
    SegTab tab, float* __restrict__ pdst,
    const int* __restrict__ ei, int* __restrict__ deg, int* __restrict__ bcnt,
    int E, int Nn, int shift, const int* __restrict__ flags, int parB) {
  __shared__ int cnt[256];
  const int bx = blockIdx.x;
  if (bx < parB) {
    int i = bx * 256 + threadIdx.x;
    if (i >= tab.total) return;
    int seg = 0;
#pragma unroll
    for (int k = 1; k < NSEG; k++)
      if (i >= tab.off[k]) seg = k;
    int j = i - tab.off[seg];
    const void* src = tab.src[seg];
    pdst[i] = flags[0] ? ((const float*)src)[j]
                       : bfbits2f((unsigned int)((const unsigned short*)src)[j]);
  } else {
    cnt[threadIdx.x] = 0;
    __syncthreads();
    const int t0 = (bx - parB) * BTILE;
    const int is64 = flags[1];
    for (int j = 0; j < 16; j++) {
      int i = t0 + threadIdx.x + j * 256;
      if (i < E) {
        int d = edge_idx(ei, (long)E + i, is64);
        if ((unsigned)d >= (unsigned)Nn) d = 0;
        atomicAdd(&deg[d], 1);
        atomicAdd(&cnt[d >> shift], 1);
      }
    }
    __syncthreads();
    int v = cnt[threadIdx.x];
    if (v > 0) atomicAdd(&bcnt[threadIdx.x], v);
  }
}

// ==== FUSED stage 2: {eff, wt, scan1} (r4, unchanged) ====
__global__ __launch_bounds__(256) void k_w1(
    const float* __restrict__ pWk, const float* __restrict__ pbk,
    const float* __restrict__ pWv, const float* __restrict__ pbv,
    const float* __restrict__ par, const float* __restrict__ pmr,
    unsigned short* __restrict__ wkeT, float* __restrict__ bke,
    unsigned short* __restrict__ wveT, float* __restrict__ bve,
    const float* __restrict__ pWq, const float* __restrict__ pWa,
    unsigned short* __restrict__ wqT, unsigned short* __restrict__ waT,
    const int* __restrict__ deg, int* __restrict__ tmp, int* __restrict__ bsum,
    int n, int effB, int wtB) {
  __shared__ int sh[256];
  const int bx = blockIdx.x;
  if (bx < effB) {
    int i = bx * 256 + threadIdx.x;
    const int total = LL * 2 * (CD + 1) * HH * DH;
    if (i >= total) return;
    int e = i & 31;
    int h = (i >> 5) & 3;
    int c = (i >> 7) % (CD + 1);
    int z = (i >> 7) / (CD + 1);
    int l = z >> 1, which = z & 1;
    const float* W = (which ? pWv : pWk) + (size_t)l * CD * CD;
    const float* B = (which ? pbv : pbk) + (size_t)l * CD;
    const float* R = (which ? pmr : par) + (size_t)l * HH * DH * DH + h * DH * DH;
    unsigned short* WoT = (which ? wveT : wkeT) + (size_t)l * CD * CD;
    float* Bo = (which ? bve : bke) + (size_t)l * CD;
    float acc = 0.f;
    if (c < CD) {
#pragma unroll
      for (int d = 0; d < DH; d++) acc += W[c * CD + h * DH + d] * R[d * DH + e];
      WoT[(size_t)(h * DH + e) * CD + c] = f2bfbits(acc);
    } else {
#pragma unroll
      for (int d = 0; d < DH; d++) acc += B[h * DH + d] * R[d * DH + e];
      Bo[h * DH + e] = acc;
    }
  } else if (bx < effB + wtB) {
    int i = (bx - effB) * 256 + threadIdx.x;  // < LL*2*CD*CD exactly
    int cin = i & 127;
    int cout = (i >> 7) & 127;
    int z = i >> 14;
    int l = z >> 1, which = z & 1;
    const float* W = (which ? pWa : pWq) + (size_t)l * CD * CD;
    unsigned short* WT = (which ? waT : wqT) + (size_t)l * CD * CD;
    WT[(size_t)cout * CD + cin] = f2bfbits(W[(size_t)cin * CD + cout]);
  } else {
    const int b = bx - effB - wtB;
    int i = b * 256 + threadIdx.x;
    int v = (i < n) ? deg[i] : 0;
    sh[threadIdx.x] = v;
    __syncthreads();
    for (int off = 1; off < 256; off <<= 1) {
      int t = (threadIdx.x >= off) ? sh[threadIdx.x - off] : 0;
      __syncthreads();
      sh[threadIdx.x] += t;
      __syncthreads();
    }
    if (i < n) tmp[i] = sh[threadIdx.x];
    if (threadIdx.x == 255) bsum[b] = sh[255];
  }
}

// ==== FUSED stage 3: {scan2, bscan} (r4, unchanged) ====
__global__ __launch_bounds__(256) void k_s2(
    int* __restrict__ bsum, int nb, const int* __restrict__ bcnt,
    int* __restrict__ bbase, int* __restrict__ bfill) {
  __shared__ int sh[256];
  __shared__ int carry;
  if (blockIdx.x == 0) {
    if (threadIdx.x == 0) carry = 0;
    __syncthreads();
    for (int base = 0; base < nb; base += 256) {
      int i = base + threadIdx.x;
      int v = (i < nb) ? bsum[i] : 0;
      sh[threadIdx.x] = v;
      __syncthreads();
      for (int off = 1; off < 256; off <<= 1) {
        int t = (threadIdx.x >= off) ? sh[threadIdx.x - off] : 0;
        __syncthreads();
        sh[threadIdx.x] += t;
        __syncthreads();
      }
      if (i < nb) bsum[i] = sh[threadIdx.x] + carry;
      __syncthreads();
      if (threadIdx.x == 0) carry += sh[255];
      __syncthreads();
    }
  } else {
    int t = threadIdx.x;
    int v = bcnt[t];
    sh[t] = v;
    __syncthreads();
    for (int off = 1; off < 256; off <<= 1) {
      int u = (t >= off) ? sh[t - off] : 0;
      __syncthreads();
      sh[t] += u;
      __syncthreads();
    }
    int excl = sh[t] - v;
    bbase[t] = excl;
    bfill[t] = excl;
  }
}

// ==== FUSED stage 4: {scan3, bin} (r4, unchanged) ====
__global__ __launch_bounds__(256) void k_s3bin(
    const int* __restrict__ tmp, const int* __restrict__ deg,
    const int* __restrict__ bsum, int* __restrict__ rowptr,
    int* __restrict__ fill, int n, int nB,
    const int* __restrict__ ei, int* __restrict__ bfill,
    int* __restrict__ ebs, int* __restrict__ ebd,
    const int* __restrict__ flags, int E, int Nn, int shift) {
  __shared__ int sS[BTILE];
  __shared__ int sD[BTILE];
  __shared__ int cnt[256], pref[256], base[256], lofs[256];
  const int bx = blockIdx.x;
  if (bx < nB) {
    int i = bx * 256 + threadIdx.x;
    if (i >= n) return;
    int off = (bx > 0) ? bsum[bx - 1] : 0;
    int excl = tmp[i] - deg[i] + off;
    rowptr[i] = excl;
    fill[i] = excl;
    return;
  }
  const int t = threadIdx.x;
  cnt[t] = 0;
  lofs[t] = 0;
  __syncthreads();
  const int t0 = (bx - nB) * BTILE;
  const int is64 = flags[1];
  for (int j = 0; j < 16; j++) {
    int i = t0 + t + j * 256;
    if (i < E) {
      int d = edge_idx(ei, (long)E + i, is64);
      if ((unsigned)d >= (unsigned)Nn) d = 0;
      atomicAdd(&cnt[d >> shift], 1);
    }
  }
  __syncthreads();
  {
    int v = cnt[t];
    pref[t] = v;
    __syncthreads();
    for (int off = 1; off < 256; off <<= 1) {
      int u = (t >= off) ? pref[t - off] : 0;
      __syncthreads();
      pref[t] += u;
      __syncthreads();
    }
    int incl = pref[t];
    __syncthreads();
    pref[t] = incl - v;
    base[t] = (v > 0) ? atomicAdd(&bfill[t], v) : 0;
  }
  __syncthreads();
  for (int j = 0; j < 16; j++) {
    int i = t0 + t + j * 256;
    if (i < E) {
      int s = edge_idx(ei, (long)i, is64);
      int d = edge_idx(ei, (long)E + i, is64);
      if ((unsigned)s >= (unsigned)Nn) s = 0;
      if ((unsigned)d >= (unsigned)Nn) d = 0;
      int b = d >> shift;
      int p = pref[b] + atomicAdd(&lofs[b], 1);
      sS[p] = s;
      sD[p] = d;
    }
  }
  __syncthreads();
  int tot = E - t0;
  if (tot > BTILE) tot = BTILE;
  for (int j = 0; j < 16; j++) {
    int i = t + j * 256;
    if (i < tot) {
      int d = sD[i];
      int b = d >> shift;
      int gp = base[b] + (i - pref[b]);
      ebs[gp] = sS[i];
      ebd[gp] = d;
    }
  }
}

// final scatter within per-bucket csr window (L2-local)
__global__ void k_scatter2(const int* __restrict__ bbase, const int* __restrict__ bcnt,
                           const int* __restrict__ ebs, const int* __restrict__ ebd,
                           int* __restrict__ fill, int* __restrict__ csr_src) {
  int b = blockIdx.x >> 1, half = blockIdx.x & 1;
  int s0 = bbase[b], c = bcnt[b];
  int st = s0 + (half ? (c + 1) / 2 : 0);
  int en = s0 + (half ? c : (c + 1) / 2);
  for (int i = st + threadIdx.x; i < en; i += 256) {
    int s = ebs[i], d = ebd[i];
    int pos = atomicAdd(&fill[d], 1);
    csr_src[pos] = s;
  }
}

// ==== fused q/k/v MFMA GEMM for layer 0, reading raw x (r5, unchanged).
// grid.y selects projection. ====
__global__ __launch_bounds__(256) void k_gemm_qkv(
    const void* __restrict__ Araw, int a_is_x, const int* __restrict__ flags,
    const unsigned short* __restrict__ wq, const unsigned short* __restrict__ wk,
    const unsigned short* __restrict__ wv,
    const float* __restrict__ bq, const float* __restrict__ bk,
    const float* __restrict__ bv,
    float* __restrict__ qout, unsigned short* __restrict__ kvout, int nrows) {
  const int which = blockIdx.y;
  const unsigned short* BT = (which == 0) ? wq : (which == 1) ? wk : wv;
  const float* bias = (which == 0) ? bq : (which == 1) ? bk : bv;
  const int w = threadIdx.x >> 6;
  const int l = threadIdx.x & 63;
  const int r0 = blockIdx.x * 64 + w * 16;
  if (r0 >= nrows) return;
  const int lrow = l & 15;
  const int quad = l >> 4;
  const int k0 = quad * 8;
  const int ax_f32 = a_is_x ? flags[0] : 0;

  f32x4 acc[8];
#pragma unroll
  for (int ct = 0; ct < 8; ct++) {
    float b = bias[ct * 16 + lrow];
    acc[ct] = (f32x4){b, b, b, b};
  }
  int ar = r0 + lrow;
  if (ar >= nrows) ar = nrows - 1;
#pragma unroll
  for (int kc = 0; kc < 4; kc++) {
    bf16x8 af;
    if (ax_f32) {
      const float* Af = (const float*)Araw + (size_t)ar * CD + kc * 32 + k0;
      float4 a = *(const float4*)Af;
      float4 b = *(const float4*)(Af + 4);
      af[0] = (short)f2bfbits(a.x); af[1] = (short)f2bfbits(a.y);
      af[2] = (short)f2bfbits(a.z); af[3] = (short)f2bfbits(a.w);
      af[4] = (short)f2bfbits(b.x); af[5] = (short)f2bfbits(b.y);
      af[6] = (short)f2bfbits(b.z); af[7] = (short)f2bfbits(b.w);
    } else {
      af = *(const bf16x8*)((const unsigned short*)Araw + (size_t)ar * CD + kc * 32 + k0);
    }
#pragma unroll
    for (int ct = 0; ct < 8; ct++) {
      bf16x8 bfr = *(const bf16x8*)(BT + (size_t)(ct * 16 + lrow) * CD + kc * 32 + k0);
      acc[ct] = __builtin_amdgcn_mfma_f32_16x16x32_bf16(af, bfr, acc[ct], 0, 0, 0);
    }
  }
#pragma unroll
  for (int ct = 0; ct < 8; ct++) {
#pragma unroll
    for (int i = 0; i < 4; i++) {
      int gr = r0 + quad * 4 + i;
      if (gr >= nrows) continue;
      int col = ct * 16 + lrow;
      float val = acc[ct][i];
      if (which == 0) {
        qout[(size_t)gr * CD + col] = val;
      } else {
        unsigned short* o = kvout + ((size_t)gr << 8) + ((which == 2) ? CD : 0);
        o[col] = f2bfbits(val);
      }
    }
  }
}

// ==== FUSED gate-l0 + qkv-l1 (r6): gate's block produces exactly the 64 rows
// the qkv block consumes -> fuse via LDS, killing the h16 round-trip
// (25.6 MB write + 3x25.6 MB read) + one dispatch boundary.
// Phase 1: gate math (identical); h f32 written (l1 residual consumer);
//          bf16-rounded tile -> LDS [64][136] (+8 pad: breaks D=128 row
//          bank-conflict, G4). Bits in LDS == bits formerly in h16.
// Phase 2: qkv-l1, A-frags from LDS; three projections SEQUENTIAL (acc regs
//          reused — avoids r3's 96-VGPR occupancy cliff). ====
__global__ __launch_bounds__(256) void k_gate_qkv(
    const unsigned short* __restrict__ A, const unsigned short* __restrict__ BTa,
    const float* __restrict__ ba, const void* __restrict__ xres,
    float* __restrict__ h, const float* __restrict__ skip,
    const int* __restrict__ flags,
    const unsigned short* __restrict__ wq1, const unsigned short* __restrict__ wk1,
    const unsigned short* __restrict__ wv1,
    const float* __restrict__ bq1, const float* __restrict__ bk1,
    const float* __restrict__ bv1,
    float* __restrict__ qout, unsigned short* __restrict__ kvout, int nrows) {
  __shared__ unsigned short sA[64][136];
  const int w = threadIdx.x >> 6;
  const int l = threadIdx.x & 63;
  const int blkbase = blockIdx.x * 64;
  const int r0 = blkbase + w * 16;
  const int lrow = l & 15;
  const int quad = l >> 4;
  const int k0 = quad * 8;
  const int xf32 = flags[0];

  // ---- phase 1: gate for this wave's 16 rows ----
  if (r0 < nrows) {
    f32x4 acc[8];
#pragma unroll
    for (int ct = 0; ct < 8; ct++) {
      float b = ba[ct * 16 + lrow];
      acc[ct] = (f32x4){b, b, b, b};
    }
    int ar = r0 + lrow;
    if (ar >= nrows) ar = nrows - 1;
    const unsigned short* Ap = A + (size_t)ar * CD;
#pragma unroll
    for (int kc = 0; kc < 4; kc++) {
      bf16x8 af = *(const bf16x8*)(Ap + kc * 32 + k0);
#pragma unroll
      for (int ct = 0; ct < 8; ct++) {
        bf16x8 bfr = *(const bf16x8*)(BTa + (size_t)(ct * 16 + lrow) * CD + kc * 32 + k0);
        acc[ct] = __builtin_amdgcn_mfma_f32_16x16x32_bf16(af, bfr, acc[ct], 0, 0, 0);
      }
    }
    float gg = 1.f / (1.f + __expf(-skip[0]));
#pragma unroll
    for (int ct = 0; ct < 8; ct++) {
#pragma unroll
      for (int i = 0; i < 4; i++) {
        int gr = r0 + quad * 4 + i;
        if (gr >= nrows) continue;
        size_t ix = (size_t)gr * CD + ct * 16 + lrow;
        float hres = xf32 ? ((const float*)xres)[ix]
                          : bfbits2f((unsigned int)((const unsigned short*)xres)[ix]);
        float o = gg * acc[ct][i] + (1.f - gg) * hres;
        h[ix] = o;
        sA[gr - blkbase][ct * 16 + lrow] = f2bfbits(o);
      }
    }
  }
  __syncthreads();
  if (r0 >= nrows) return;

  // ---- phase 2: qkv-l1 from LDS ----
  int ar = r0 + lrow;
  if (ar >= nrows) ar = nrows - 1;
  const unsigned short* Alds = &sA[ar - blkbase][0];
#pragma unroll
  for (int which = 0; which < 3; which++) {
    const unsigned short* BT = (which == 0) ? wq1 : (which == 1) ? wk1 : wv1;
    const float* bias = (which == 0) ? bq1 : (which == 1) ? bk1 : bv1;
    f32x4 acc[8];
#pragma unroll
    for (int ct = 0; ct < 8; ct++) {
      float b = bias[ct * 16 + lrow];
      acc[ct] = (f32x4){b, b, b, b};
    }
#pragma unroll
    for (int kc = 0; kc < 4; kc++) {
      bf16x8 af = *(const bf16x8*)(Alds + kc * 32 + k0);
#pragma unroll
      for (int ct = 0; ct < 8; ct++) {
        bf16x8 bfr = *(const bf16x8*)(BT + (size_t)(ct * 16 + lrow) * CD + kc * 32 + k0);
        acc[ct] = __builtin_amdgcn_mfma_f32_16x16x32_bf16(af, bfr, acc[ct], 0, 0, 0);
      }
    }
#pragma unroll
    for (int ct = 0; ct < 8; ct++) {
#pragma unroll
      for (int i = 0; i < 4; i++) {
        int gr = r0 + quad * 4 + i;
        if (gr >= nrows) continue;
        int col = ct * 16 + lrow;
        float val = acc[ct][i];
        if (which == 0) {
          qout[(size_t)gr * CD + col] = val;
        } else {
          unsigned short* o = kvout + ((size_t)gr << 8) + ((which == 2) ? CD : 0);
          o[col] = f2bfbits(val);
        }
      }
    }
  }
}

// ==== gate MFMA GEMM, FINAL layer only (r6): gelu(agg)@Wa + ba, gated
// residual from h f32, fused 128x2 output projection (r5, passed). ====
__global__ __launch_bounds__(256) void k_gemm_gate(
    const unsigned short* __restrict__ A, const unsigned short* __restrict__ BT,
    const float* __restrict__ bias, const float* __restrict__ h,
    const float* __restrict__ skip,
    const float* __restrict__ Wfc, const float* __restrict__ bfc,
    void* __restrict__ out, const int* __restrict__ flags, int nrows) {
  const int w = threadIdx.x >> 6;
  const int l = threadIdx.x & 63;
  const int r0 = blockIdx.x * 64 + w * 16;
  if (r0 >= nrows) return;
  const int lrow = l & 15;
  const int quad = l >> 4;
  const int k0 = quad * 8;
  const int xf32 = flags[0];

  f32x4 acc[8];
#pragma unroll
  for (int ct = 0; ct < 8; ct++) {
    float b = bias[ct * 16 + lrow];
    acc[ct] = (f32x4){b, b, b, b};
  }
  int ar = r0 + lrow;
  if (ar >= nrows) ar = nrows - 1;
  const unsigned short* Ap = A + (size_t)ar * CD;
#pragma unroll
  for (int kc = 0; kc < 4; kc++) {
    bf16x8 af = *(const bf16x8*)(Ap + kc * 32 + k0);
#pragma unroll
    for (int ct = 0; ct < 8; ct++) {
      bf16x8 bfr = *(const bf16x8*)(BT + (size_t)(ct * 16 + lrow) * CD + kc * 32 + k0);
      acc[ct] = __builtin_amdgcn_mfma_f32_16x16x32_bf16(af, bfr, acc[ct], 0, 0, 0);
    }
  }
  float gg = 1.f / (1.f + __expf(-skip[0]));
  float p0[4] = {0.f, 0.f, 0.f, 0.f};
  float p1[4] = {0.f, 0.f, 0.f, 0.f};
#pragma unroll
  for (int ct = 0; ct < 8; ct++) {
    float w0 = Wfc[(ct * 16 + lrow) * 2];
    float w1 = Wfc[(ct * 16 + lrow) * 2 + 1];
#pragma unroll
    for (int i = 0; i < 4; i++) {
      int gr = r0 + quad * 4 + i;
      if (gr >= nrows) continue;
      size_t ix = (size_t)gr * CD + ct * 16 + lrow;
      float o = gg * acc[ct][i] + (1.f - gg) * h[ix];
      p0[i] += o * w0;
      p1[i] += o * w1;
    }
  }
#pragma unroll
  for (int off = 1; off <= 8; off <<= 1) {
#pragma unroll
    for (int i = 0; i < 4; i++) {
      p0[i] += __shfl_xor(p0[i], off);
      p1[i] += __shfl_xor(p1[i], off);
    }
  }
  if (lrow == 0) {
#pragma unroll
    for (int i = 0; i < 4; i++) {
      int gr = r0 + quad * 4 + i;
      if (gr >= nrows) continue;
      float o0 = p0[i] + bfc[0];
      float o1 = p1[i] + bfc[1];
      if (xf32) {
        ((float*)out)[(size_t)gr * 2] = o0;
        ((float*)out)[(size_t)gr * 2 + 1] = o1;
      } else {
        ((bf16*)out)[(size_t)gr * 2] = __float2bfloat16(o0);
        ((bf16*)out)[(size_t)gr * 2 + 1] = __float2bfloat16(o1);
      }
    }
  }
}

// ---- per-edge compute: unpack k/v, dot with q, exp, accumulate ----
__device__ __forceinline__ void edge_acc(uint4 ku, uint4 vu, float4 qa, float4 qb,
                                         float* __restrict__ acc, float& den) {
  float k0 = bfbits2f(ku.x & 0xffffu), k1 = bfbits2f(ku.x >> 16);
  float k2 = bfbits2f(ku.y & 0xffffu), k3 = bfbits2f(ku.y >> 16);
  float k4 = bfbits2f(ku.z & 0xffffu), k5 = bfbits2f(ku.z >> 16);
  float k6 = bfbits2f(ku.w & 0xffffu), k7 = bfbits2f(ku.w >> 16);
  float v0 = bfbits2f(vu.x & 0xffffu), v1 = bfbits2f(vu.x >> 16);
  float v2 = bfbits2f(vu.y & 0xffffu), v3 = bfbits2f(vu.y >> 16);
  float v4 = bfbits2f(vu.z & 0xffffu), v5 = bfbits2f(vu.z >> 16);
  float v6 = bfbits2f(vu.w & 0xffffu), v7 = bfbits2f(vu.w >> 16);
  float pd = qa.x * k0 + qa.y * k1 + qa.z * k2 + qa.w * k3 +
             qb.x * k4 + qb.y * k5 + qb.z * k6 + qb.w * k7;
  pd += __shfl_xor(pd, 1);
  pd += __shfl_xor(pd, 2);
  float ew = __expf(fminf(pd, 60.f));  // no max-sub: |logit| ~ O(1), safe
  acc[0] += ew * v0; acc[1] += ew * v1;
  acc[2] += ew * v2; acc[3] += ew * v3;
  acc[4] += ew * v4; acc[5] += ew * v5;
  acc[6] += ew * v6; acc[7] += ew * v7;
  den += ew;
}

// ==== fused attention (unchanged; pinned at the random-256B-gather
// throughput ceiling ~3.75 TB/s across 3 schedules / occupancies 67-77%). ====
__global__ __launch_bounds__(256) void k_edge(
    const float* __restrict__ q, const unsigned short* __restrict__ kv,
    const int* __restrict__ rowptr, const int* __restrict__ deg,
    const int* __restrict__ csr_src, const float* __restrict__ p_rel,
    unsigned short* __restrict__ agg16, int N) {
  int n = (blockIdx.x * 256 + threadIdx.x) >> 6;
  if (n >= N) return;
  const int lane = threadIdx.x & 63;
  const int g = lane >> 4;
  const int j = lane & 15;
  const int start = rowptr[n];
  const int end = start + deg[n];
  const float prl = p_rel[j >> 2] * 0.17677669529663687f;  // 1/sqrt(32)
  float4 qa = *(const float4*)(q + (size_t)n * CD + 8 * j);
  float4 qb = *(const float4*)(q + (size_t)n * CD + 8 * j + 4);
  qa.x *= prl; qa.y *= prl; qa.z *= prl; qa.w *= prl;
  qb.x *= prl; qb.y *= prl; qb.z *= prl; qb.w *= prl;
  float den = 0.f;
  float acc[8] = {0.f, 0.f, 0.f, 0.f, 0.f, 0.f, 0.f, 0.f};
  int e = start + g;
  if (e < end) {
    const int last = end - 1;
    bool bok = (e + 4) < end;
    int sa = csr_src[e];
    int sb = csr_src[bok ? e + 4 : e];
    const unsigned short* pa = kv + ((size_t)sa << 8) + 8 * j;
    const unsigned short* pb = kv + ((size_t)sb << 8) + 8 * j;
    uint4 kua = *(const uint4*)pa;
    uint4 vua = *(const uint4*)(pa + CD);
    uint4 kub = *(const uint4*)pb;
    uint4 vub = *(const uint4*)(pb + CD);
    for (;;) {
      const int en = e + 8;
      int ea2 = (en < last) ? en : last;
      int eb2 = (en + 4 < last) ? en + 4 : last;
      int sa2 = csr_src[ea2];
      int sb2 = csr_src[eb2];
      const unsigned short* pa2 = kv + ((size_t)sa2 << 8) + 8 * j;
      const unsigned short* pb2 = kv + ((size_t)sb2 << 8) + 8 * j;
      uint4 kua2 = *(const uint4*)pa2;
      uint4 vua2 = *(const uint4*)(pa2 + CD);
      uint4 kub2 = *(const uint4*)pb2;
      uint4 vub2 = *(const uint4*)(pb2 + CD);
      __builtin_amdgcn_sched_barrier(0);
      edge_acc(kua, vua, qa, qb, acc, den);
      if (bok) edge_acc(kub, vub, qa, qb, acc, den);
      if (en >= end) break;
      e = en;
      bok = (en + 4) < end;
      kua = kua2; vua = vua2; kub = kub2; vub = vub2;
    }
  }
#pragma unroll
  for (int off = 16; off <= 32; off <<= 1) {
    den += __shfl_xor(den, off);
#pragma unroll
    for (int i = 0; i < 8; i++) acc[i] += __shfl_xor(acc[i], off);
  }
  if (g == 0) {
    float inv = (den > 0.f) ? 1.f / den : 0.f;
    ushort4 o0, o1;
    o0.x = f2bfbits(gelu_f(acc[0] * inv)); o0.y = f2bfbits(gelu_f(acc[1] * inv));
    o0.z = f2bfbits(gelu_f(acc[2] * inv)); o0.w = f2bfbits(gelu_f(acc[3] * inv));
    o1.x = f2bfbits(gelu_f(acc[4] * inv)); o1.y = f2bfbits(gelu_f(acc[5] * inv));
    o1.z = f2bfbits(gelu_f(acc[6] * inv)); o1.w = f2bfbits(gelu_f(acc[7] * inv));
    *(ushort4*)(agg16 + (size_t)n * CD + 8 * j) = o0;
    *(ushort4*)(agg16 + (size_t)n * CD + 8 * j + 4) = o1;
  }
}

extern "C" void kernel_launch(void* const* d_in, const int* in_sizes, int n_in,
                              void* d_out, int out_size, void* d_ws, size_t ws_size,
                              hipStream_t stream) {
  const int* ei = (const int*)d_in[1];
  const int N = in_sizes[0] / CD;
  const int E = in_sizes[1] / 2;
  const size_t NC = (size_t)N * CD;
  const int nB = (N + 255) / 256;
  int shift = 0;
  while (((N - 1) >> shift) >= 256) shift++;  // 256 coarse buckets

  float* p = (float*)d_ws;
  float* hbuf = p;                                    // NC f32 (h1 storage)
  float* qbuf = p + NC;                               // NC f32
  float* cur = p + 2 * NC;
  unsigned short* kvbuf16 = (unsigned short*)cur; cur += NC;  // N x 256 bf16 (k|v)
  unsigned short* agg16 = (unsigned short*)cur; cur += NC / 2;
  int* ip = (int*)cur;
  int* deg = ip;
  int* tmp = ip + N;
  int* rowptr = ip + 2 * N;
  int* fill = ip + 3 * N;
  int* bsum = ip + 4 * N;
  int* csr_src = ip + 4 * N + nB;
  int* bcnt = csr_src + E;     // 256
  int* bbase = bcnt + 256;     // 256
  int* bfill = bbase + 256;    // 256
  cur = (float*)(bfill + 256);
  unsigned short* wkeT = (unsigned short*)cur; cur += (size_t)LL * CD * CD / 2;
  unsigned short* wveT = (unsigned short*)cur; cur += (size_t)LL * CD * CD / 2;
  unsigned short* wqT = (unsigned short*)cur; cur += (size_t)LL * CD * CD / 2;
  unsigned short* waT = (unsigned short*)cur; cur += (size_t)LL * CD * CD / 2;
  float* bke = cur; cur += (size_t)LL * CD;
  float* bve = cur; cur += (size_t)LL * CD;
  float* pblock = cur;
  float* pWk = cur; cur += (size_t)LL * CD * CD;
  float* pbk = cur; cur += (size_t)LL * CD;
  float* pWq = cur; cur += (size_t)LL * CD * CD;
  float* pbq = cur; cur += (size_t)LL * CD;
  float* pWv = cur; cur += (size_t)LL * CD * CD;
  float* pbv = cur; cur += (size_t)LL * CD;
  float* par = cur; cur += (size_t)LL * HH * DH * DH;
  float* pmr = cur; cur += (size_t)LL * HH * DH * DH;
  float* ppr = cur; cur += (size_t)LL * HH;
  float* pWa = cur; cur += (size_t)LL * CD * CD;
  float* pba = cur; cur += (size_t)LL * CD;
  float* pskip = cur; cur += LL;
  float* pWfc = cur; cur += (size_t)CD * 2;
  float* pbfc = cur; cur += 2;
  int* flags = (int*)cur;

  // binned-edge staging aliases kvbuf16 (only used before layer loop)
  int* ebs = (int*)kvbuf16;      // E ints
  int* ebd = ebs + E;            // E ints

  SegTab tab;
  const int sizes[NSEG] = {LL * CD * CD, LL * CD, LL * CD * CD, LL * CD,
                           LL * CD * CD, LL * CD, LL * HH * DH * DH,
                           LL * HH * DH * DH, LL * HH, LL * CD * CD, LL * CD,
                           LL, CD * 2, 2};
  const int srcIdx[NSEG] = {2, 3, 4, 5, 6, 7, 8, 9, 10, 11, 12, 13, 14, 15};
  int off = 0;
  for (int k = 0; k < NSEG; k++) {
    tab.src[k] = d_in[srcIdx[k]];
    tab.off[k] = off;
    off += sizes[k];
  }
  tab.total = off;

  hipMemsetAsync(deg, 0, (size_t)N * sizeof(int), stream);
  hipMemsetAsync(bcnt, 0, 256 * sizeof(int), stream);
  k_detect<<<1, 128, 0, stream>>>(d_in[0], ei, flags);

  const int parB = (tab.total + 255) / 256;
  const int histB = (E + BTILE - 1) / BTILE;
  k_pre<<<parB + histB, 256, 0, stream>>>(tab, pblock, ei, deg, bcnt, E, N,
                                          shift, flags, parB);

  const int effB = (LL * 2 * (CD + 1) * HH * DH + 255) / 256;
  const int wtB = (LL * 2 * CD * CD) / 256;
  k_w1<<<effB + wtB + nB, 256, 0, stream>>>(
      pWk, pbk, pWv, pbv, par, pmr, wkeT, bke, wveT, bve,
      pWq, pWa, wqT, waT, deg, tmp, bsum, N, effB, wtB);

  k_s2<<<2, 256, 0, stream>>>(bsum, nB, bcnt, bbase, bfill);
  k_s3bin<<<nB + histB, 256, 0, stream>>>(tmp, deg, bsum, rowptr, fill, N, nB,
                                          ei, bfill, ebs, ebd, flags, E, N, shift);
  k_scatter2<<<512, 256, 0, stream>>>(bbase, bcnt, ebs, ebd, fill, csr_src);

  const int mfmaBlocks = (N + 63) / 64;

  // layer 0 qkv (from raw x)
  k_gemm_qkv<<<dim3(mfmaBlocks, 3), 256, 0, stream>>>(
      d_in[0], 1, flags, wqT, wkeT, wveT, pbq, bke, bve, qbuf, kvbuf16, N);

  // layer 0 edge attention
  k_edge<<<(N + 3) / 4, 256, 0, stream>>>(qbuf, kvbuf16, rowptr, deg,
                                          csr_src, ppr, agg16, N);

  // fused: gate-l0 (residual from x) + qkv-l1 (A from LDS)
  k_gate_qkv<<<mfmaBlocks, 256, 0, stream>>>(
      agg16, waT, pba, d_in[0], hbuf, pskip, flags,
      wqT + (size_t)CD * CD, wkeT + (size_t)CD * CD, wveT + (size_t)CD * CD,
      pbq + CD, bke + CD, bve + CD, qbuf, kvbuf16, N);

  // layer 1 edge attention
  k_edge<<<(N + 3) / 4, 256, 0, stream>>>(qbuf, kvbuf16, rowptr, deg,
                                          csr_src, ppr + HH, agg16, N);

  // layer 1 gate + fused final projection
  k_gemm_gate<<<mfmaBlocks, 256, 0, stream>>>(
      agg16, waT + (size_t)CD * CD, pba + CD, hbuf, pskip + 1,
      pWfc, pbfc, d_out, flags, N);
}